// Round 1
// baseline (1540.921 us; speedup 1.0000x reference)
//
#include <hip/hip_runtime.h>
#include <cstdint>
#include <cstddef>

#define T_ 256
#define HN_ 4096
#define H_ 32
#define N_ 128

typedef __attribute__((ext_vector_type(8))) short short8;
typedef __attribute__((ext_vector_type(4))) float f32x4;

__device__ __forceinline__ short f2bf(float f) {
    uint32_t u = __builtin_bit_cast(uint32_t, f);
    u = (u + 0x7fffu + ((u >> 16) & 1u)) >> 16;   // RNE f32->bf16
    return (short)u;
}

__device__ __forceinline__ void ld8(float* d, const float* p) {
    float4 lo = *(const float4*)p, hi = *(const float4*)(p + 4);
    d[0] = lo.x; d[1] = lo.y; d[2] = lo.z; d[3] = lo.w;
    d[4] = hi.x; d[5] = hi.y; d[6] = hi.z; d[7] = hi.w;
}

__device__ __forceinline__ float sigm(float x) { return 1.f / (1.f + expf(-x)); }
__device__ __forceinline__ float splus(float x) { return (x > 20.f) ? x : log1pf(expf(x)); }

// ---------------- RMSNorm over 4096 (t5 style) ----------------
__global__ __launch_bounds__(256) void rmsnorm_k(const float* __restrict__ in,
                                                 const float* __restrict__ w,
                                                 float* __restrict__ out,
                                                 float* __restrict__ lastrow) {
    int t = blockIdx.x, tid = threadIdx.x;
    const float4* in4 = (const float4*)(in + (size_t)t * HN_);
    const float4* w4 = (const float4*)w;
    float4 v[4]; float ss = 0.f;
#pragma unroll
    for (int q = 0; q < 4; q++) {
        v[q] = in4[q * 256 + tid];
        ss += v[q].x * v[q].x + v[q].y * v[q].y + v[q].z * v[q].z + v[q].w * v[q].w;
    }
#pragma unroll
    for (int o = 32; o; o >>= 1) ss += __shfl_down(ss, o);
    __shared__ float red[4];
    if ((tid & 63) == 0) red[tid >> 6] = ss;
    __syncthreads();
    float tot = red[0] + red[1] + red[2] + red[3];
    float sc = rsqrtf(tot * (1.f / HN_) + 1e-6f);
    float4* o4 = (float4*)(out + (size_t)t * HN_);
#pragma unroll
    for (int q = 0; q < 4; q++) {
        float4 wv = w4[q * 256 + tid];
        float4 r;
        r.x = wv.x * v[q].x * sc; r.y = wv.y * v[q].y * sc;
        r.z = wv.z * v[q].z * sc; r.w = wv.w * v[q].w * sc;
        o4[q * 256 + tid] = r;
        if (lastrow != nullptr && t == T_ - 1) ((float4*)lastrow)[q * 256 + tid] = r;
    }
}

// ---------------- bf16 MFMA GEMM: C[m][n] = sum_k A[m][k]*B(k,n) (+bias +resid) ----
// BMAJOR==0: B stored as W[n*ldb + k] (k-contiguous rows = TN)
// BMAJOR==1: B stored as W[k*ldb + n] (n-contiguous rows = NN)
template <int BMAJOR>
__global__ __launch_bounds__(256) void gemm_bf16(
    const float* __restrict__ A, int lda,
    const float* __restrict__ B, int ldb,
    const float* __restrict__ bias,
    const float* __restrict__ resid,
    float* __restrict__ C, int ldc,
    int M, int N, int K) {
    const int tid = threadIdx.x;
    const int wid = tid >> 6;
    const int l = tid & 63;
    const int ar = l & 15;
    const int ak = (l >> 4) * 8;
    const int wm = wid >> 1, wn = wid & 1;
    const int mBase = blockIdx.x * 128 + wm * 64;
    const int nBase = blockIdx.y * 64 + wn * 32;

    f32x4 acc[4][2];
#pragma unroll
    for (int i = 0; i < 4; i++)
#pragma unroll
        for (int j = 0; j < 2; j++) acc[i][j] = f32x4{0.f, 0.f, 0.f, 0.f};

    for (int k0 = 0; k0 < K; k0 += 32) {
        short8 af[4];
#pragma unroll
        for (int i = 0; i < 4; i++) {
            const float* p = A + (size_t)(mBase + i * 16 + ar) * lda + (k0 + ak);
            float4 lo = *(const float4*)p, hi = *(const float4*)(p + 4);
            short8 v;
            v[0] = f2bf(lo.x); v[1] = f2bf(lo.y); v[2] = f2bf(lo.z); v[3] = f2bf(lo.w);
            v[4] = f2bf(hi.x); v[5] = f2bf(hi.y); v[6] = f2bf(hi.z); v[7] = f2bf(hi.w);
            af[i] = v;
        }
        short8 bfr[2];
#pragma unroll
        for (int j = 0; j < 2; j++) {
            int col = nBase + j * 16 + ar;
            short8 v;
            if (BMAJOR == 0) {
                const float* p = B + (size_t)col * ldb + (k0 + ak);
                float4 lo = *(const float4*)p, hi = *(const float4*)(p + 4);
                v[0] = f2bf(lo.x); v[1] = f2bf(lo.y); v[2] = f2bf(lo.z); v[3] = f2bf(lo.w);
                v[4] = f2bf(hi.x); v[5] = f2bf(hi.y); v[6] = f2bf(hi.z); v[7] = f2bf(hi.w);
            } else {
                const float* p = B + (size_t)(k0 + ak) * ldb + col;
#pragma unroll
                for (int e = 0; e < 8; e++) v[e] = f2bf(p[(size_t)e * ldb]);
            }
            bfr[j] = v;
        }
#pragma unroll
        for (int i = 0; i < 4; i++)
#pragma unroll
            for (int j = 0; j < 2; j++)
                acc[i][j] = __builtin_amdgcn_mfma_f32_16x16x32_bf16(af[i], bfr[j], acc[i][j], 0, 0, 0);
    }

    const int rl = (l >> 4) * 4;
    const int cl = l & 15;
#pragma unroll
    for (int i = 0; i < 4; i++) {
#pragma unroll
        for (int j = 0; j < 2; j++) {
            int col = nBase + j * 16 + cl;
            float bv = bias ? bias[col] : 0.f;
#pragma unroll
            for (int e = 0; e < 4; e++) {
                int row = mBase + i * 16 + rl + e;
                float v = acc[i][j][e] + bv;
                if (resid) v += resid[(size_t)row * ldc + col];
                C[(size_t)row * ldc + col] = v;
            }
        }
    }
}

// ---------------- LoRA stage-1 (f32): tcat = [tanh(x@w1) | x@a1 | x@v1 | sigm(x@g1)] ----
__global__ __launch_bounds__(256) void lora1_k(const float* __restrict__ x,
                                               const float* __restrict__ w1p,
                                               const float* __restrict__ a1p,
                                               const float* __restrict__ v1p,
                                               const float* __restrict__ g1p,
                                               float* __restrict__ tcat) {
    int m = blockIdx.x, tid = threadIdx.x;
    __shared__ float xs[HN_];
    const float4* x4 = (const float4*)(x + (size_t)m * HN_);
#pragma unroll
    for (int q = 0; q < 4; q++) ((float4*)xs)[q * 256 + tid] = x4[q * 256 + tid];
    __syncthreads();
    for (int c = tid; c < 288; c += 256) {
        const float* Wp; int ldw, nn, mode;
        if (c < 64)       { Wp = w1p; ldw = 64;  nn = c;       mode = 1; }
        else if (c < 128) { Wp = a1p; ldw = 64;  nn = c - 64;  mode = 0; }
        else if (c < 160) { Wp = v1p; ldw = 32;  nn = c - 128; mode = 0; }
        else              { Wp = g1p; ldw = 128; nn = c - 160; mode = 2; }
        float s0 = 0.f, s1 = 0.f, s2 = 0.f, s3 = 0.f;
        for (int kk = 0; kk < 1024; kk++) {
            s0 = fmaf(xs[kk],        Wp[(size_t)kk * ldw + nn],          s0);
            s1 = fmaf(xs[kk + 1024], Wp[(size_t)(kk + 1024) * ldw + nn], s1);
            s2 = fmaf(xs[kk + 2048], Wp[(size_t)(kk + 2048) * ldw + nn], s2);
            s3 = fmaf(xs[kk + 3072], Wp[(size_t)(kk + 3072) * ldw + nn], s3);
        }
        float r = (s0 + s1) + (s2 + s3);
        if (mode == 1) r = tanhf(r);
        else if (mode == 2) r = sigm(r);
        tcat[(size_t)m * 288 + c] = r;
    }
}

// ---------------- RoPE cos/sin table [T][64] ----------------
__global__ void rope_k(const int* __restrict__ cpos, float* __restrict__ cosT,
                       float* __restrict__ sinT) {
    int idx = blockIdx.x * 256 + threadIdx.x;   // 16384 total
    int t = idx >> 6, f = idx & 63;
    float pos = (float)cpos[0] + (float)t;
    float mix = fminf(fmaxf(pos * (1.f / 4096.f), 0.f), 1.f);
    float e = (float)f * (1.f / 64.f);
    float inv_s = exp2f(-13.287712379549449f * e);                         // 10000^-e
    float inv_l = exp2f(-13.287712379549449f - 3.321928094887362f * e);    // 1/(10000*10^e)
    float fr = pos * ((1.f - mix) * inv_s + mix * inv_l);
    cosT[idx] = cosf(fr);
    sinT[idx] = sinf(fr);
}

// ---------------- elementwise prep: per-head rmsnorm + rope + gates -> scan layout ----
__global__ __launch_bounds__(256) void prep_k(
    const float* __restrict__ r_raw, const float* __restrict__ k_raw,
    const float* __restrict__ v_raw, const float* __restrict__ wpre,
    const float* __restrict__ apre, const float* __restrict__ vgpre,
    const float* __restrict__ vfirst, const float* __restrict__ cosT,
    const float* __restrict__ sinT, const float* __restrict__ lnr,
    const float* __restrict__ lnk,
    float* __restrict__ rf, float* __restrict__ wf, float* __restrict__ kf,
    float* __restrict__ vf, float* __restrict__ raf, float* __restrict__ rbf) {
    int t = blockIdx.x, tid = threadIdx.x;
    int w = tid >> 6, lane = tid & 63;
    float c = cosT[t * 64 + lane], s = sinT[t * 64 + lane];
    float lr0 = lnr[lane], lr1 = lnr[lane + 64];
    float lk0 = lnk[lane], lk1 = lnk[lane + 64];
    for (int hb = 0; hb < 8; hb++) {
        int h = hb * 4 + w;
        int kv = h >> 2;
        // ---- r: per-head rmsnorm + rope
        float r0 = r_raw[(size_t)t * HN_ + h * 128 + lane];
        float r1 = r_raw[(size_t)t * HN_ + h * 128 + 64 + lane];
        float ssum = r0 * r0 + r1 * r1;
#pragma unroll
        for (int o = 32; o; o >>= 1) ssum += __shfl_xor(ssum, o);
        float sc = rsqrtf(ssum * (1.f / 128.f) + 1e-6f);
        float rn0 = lr0 * r0 * sc, rn1 = lr1 * r1 * sc;
        float rr0 = rn0 * c - rn1 * s;
        float rr1 = rn1 * c + rn0 * s;
        // ---- k: per-kv-head rmsnorm + rope (redundant across the 4 repeats, fine)
        float k0 = k_raw[(size_t)t * 1024 + kv * 128 + lane];
        float k1 = k_raw[(size_t)t * 1024 + kv * 128 + 64 + lane];
        float ks = k0 * k0 + k1 * k1;
#pragma unroll
        for (int o = 32; o; o >>= 1) ks += __shfl_xor(ks, o);
        float ksc = rsqrtf(ks * (1.f / 128.f) + 1e-6f);
        float kn0 = lk0 * k0 * ksc, kn1 = lk1 * k1 * ksc;
        float kr0 = kn0 * c - kn1 * s;
        float kr1 = kn1 * c + kn0 * s;
        // ---- kk = k / max(||k||, 1e-12)
        float nr = kr0 * kr0 + kr1 * kr1;
#pragma unroll
        for (int o = 32; o; o >>= 1) nr += __shfl_xor(nr, o);
        float inv = 1.f / fmaxf(sqrtf(nr), 1e-12f);
        float kk0 = kr0 * inv, kk1 = kr1 * inv;
        // ---- per-channel gates
        int c0 = h * 128 + lane, c1 = c0 + 64;
        size_t tb = (size_t)t * HN_;
        size_t ob = (size_t)h * (T_ * 128) + (size_t)t * 128 + lane;

        float wv0 = -splus(-wpre[tb + c0]) - 0.5f;
        float wv1 = -splus(-wpre[tb + c1]) - 0.5f;
        float dec0 = expf(-expf(wv0));
        float dec1 = expf(-expf(wv1));
        float av0 = sigm(apre[tb + c0]);
        float av1 = sigm(apre[tb + c1]);
        float vg0 = sigm(vgpre[tb + c0]);
        float vg1 = sigm(vgpre[tb + c1]);
        float vraw0 = v_raw[(size_t)t * 1024 + kv * 128 + lane];
        float vraw1 = v_raw[(size_t)t * 1024 + kv * 128 + 64 + lane];
        float vf0 = vraw0 + (vfirst[tb + c0] - vraw0) * vg0;
        float vf1 = vraw1 + (vfirst[tb + c1] - vraw1) * vg1;

        rf[ob] = rr0;            rf[ob + 64] = rr1;
        wf[ob] = dec0;           wf[ob + 64] = dec1;
        kf[ob] = kr0 * (1.f - wv0 + av0);
        kf[ob + 64] = kr1 * (1.f - wv1 + av1);
        vf[ob] = vf0;            vf[ob + 64] = vf1;
        raf[ob] = -kk0;          raf[ob + 64] = -kk1;
        rbf[ob] = kk0 * av0;     rbf[ob + 64] = kk1 * av1;
    }
}

// ---------------- sequential scan: 256 blocks = (8 row-splits x 32 heads) ----------
__global__ __launch_bounds__(256) void scan_k(
    const float* __restrict__ state_in,
    const float* __restrict__ rf, const float* __restrict__ wf,
    const float* __restrict__ kf, const float* __restrict__ vf,
    const float* __restrict__ raf, const float* __restrict__ rbf,
    const float* __restrict__ rk, const float* __restrict__ g,
    float* __restrict__ y, float* __restrict__ Sout) {
    int sp = blockIdx.x, h = blockIdx.y;
    int tid = threadIdx.x;
    int il = tid >> 4, jq = tid & 15;
    int i = sp * 16 + il, j0 = jq * 8;

    float S[8];
    ld8(S, state_in + ((size_t)h * 128 + i) * 128 + j0);
    float rk8[8];
    ld8(rk8, rk + h * 128 + j0);
    size_t hb = (size_t)h * (T_ * 128);

    struct V8 { float a[8], b[8], k[8], w[8], r[8]; float vi; };
    V8 bufA, bufB;
    auto LOAD = [&](V8& d, int t) {
        size_t base = hb + (size_t)t * 128;
        ld8(d.a, raf + base + j0);
        ld8(d.b, rbf + base + j0);
        ld8(d.k, kf + base + j0);
        ld8(d.w, wf + base + j0);
        ld8(d.r, rf + base + j0);
        d.vi = vf[base + i];
    };
    auto STEP = [&](V8& u, int t) {
        float sa = 0.f;
#pragma unroll
        for (int e = 0; e < 8; e++) sa = fmaf(S[e], u.a[e], sa);
        sa += __shfl_xor(sa, 1); sa += __shfl_xor(sa, 2);
        sa += __shfl_xor(sa, 4); sa += __shfl_xor(sa, 8);
        float od = 0.f, bd = 0.f;
#pragma unroll
        for (int e = 0; e < 8; e++) {
            S[e] = fmaf(u.vi, u.k[e], fmaf(sa, u.b[e], S[e] * u.w[e]));
            od = fmaf(S[e], u.r[e], od);
            bd = fmaf(u.r[e] * u.k[e], rk8[e], bd);
        }
        od += __shfl_xor(od, 1); od += __shfl_xor(od, 2);
        od += __shfl_xor(od, 4); od += __shfl_xor(od, 8);
        bd += __shfl_xor(bd, 1); bd += __shfl_xor(bd, 2);
        bd += __shfl_xor(bd, 4); bd += __shfl_xor(bd, 8);
        if (jq == 0) {
            size_t oi = (size_t)t * HN_ + h * 128 + i;
            y[oi] = (od * 0.08838834764831845f + bd * u.vi) * g[oi];
        }
    };

    LOAD(bufA, 0);
    for (int t = 0; t < T_; t += 2) {
        LOAD(bufB, t + 1);
        STEP(bufA, t);
        if (t + 2 < T_) LOAD(bufA, t + 2);
        STEP(bufB, t + 1);
    }
    float* p = Sout + ((size_t)h * 128 + i) * 128 + j0;
    *(float4*)p = make_float4(S[0], S[1], S[2], S[3]);
    *(float4*)(p + 4) = make_float4(S[4], S[5], S[6], S[7]);
}

// =====================================================================================
extern "C" void kernel_launch(void* const* d_in, const int* in_sizes, int n_in,
                              void* d_out, int out_size, void* d_ws, size_t ws_size,
                              hipStream_t stream) {
    const float* x_in   = (const float*)d_in[0];
    const float* vfirst = (const float*)d_in[1];
    const float* state  = (const float*)d_in[2];
    const int*   cpos   = (const int*)d_in[3];
    const float* w0 = (const float*)d_in[4];
    const float* w1 = (const float*)d_in[5];
    const float* w2 = (const float*)d_in[6];
    const float* a0 = (const float*)d_in[7];
    const float* a1 = (const float*)d_in[8];
    const float* a2 = (const float*)d_in[9];
    const float* v0 = (const float*)d_in[10];
    const float* v1 = (const float*)d_in[11];
    const float* v2 = (const float*)d_in[12];
    const float* g1 = (const float*)d_in[13];
    const float* g2 = (const float*)d_in[14];
    const float* r_k = (const float*)d_in[15];
    const float* R_ = (const float*)d_in[16];
    const float* K_ = (const float*)d_in[17];
    const float* V_ = (const float*)d_in[18];
    const float* O_ = (const float*)d_in[19];
    const float* Rb = (const float*)d_in[20];
    const float* Kb = (const float*)d_in[21];
    const float* Vb = (const float*)d_in[22];
    const float* ln_r = (const float*)d_in[23];
    const float* ln_k = (const float*)d_in[24];
    const float* ln1 = (const float*)d_in[25];
    const float* ln2 = (const float*)d_in[26];

    float* ws = (float*)d_ws;
    constexpr size_t OFF_X    = 0;
    constexpr size_t OFF_RRAW = 1048576;
    constexpr size_t OFF_KRAW = 2097152;
    constexpr size_t OFF_VRAW = 2359296;
    constexpr size_t OFF_TCAT = 2621440;
    constexpr size_t OFF_WPRE = 2695168;
    constexpr size_t OFF_APRE = 3743744;
    constexpr size_t OFF_VGPRE= 4792320;
    constexpr size_t OFF_G    = 5840896;
    constexpr size_t OFF_COS  = 6889472;
    constexpr size_t OFF_SIN  = 6905856;
    constexpr size_t OFF_RF   = 6922240;
    constexpr size_t OFF_WF   = 7970816;
    constexpr size_t OFF_KF   = 9019392;
    constexpr size_t OFF_VF   = 10067968;
    constexpr size_t OFF_AF   = 11116544;
    constexpr size_t OFF_BF   = 12165120;
    constexpr size_t OFF_Y    = 13213696;

    float* X    = ws + OFF_X;
    float* RRAW = ws + OFF_RRAW;
    float* KRAW = ws + OFF_KRAW;
    float* VRAW = ws + OFF_VRAW;
    float* TCAT = ws + OFF_TCAT;
    float* WPRE = ws + OFF_WPRE;
    float* APRE = ws + OFF_APRE;
    float* VGPRE= ws + OFF_VGPRE;
    float* GARR = ws + OFF_G;
    float* COST = ws + OFF_COS;
    float* SINT = ws + OFF_SIN;
    float* RF = ws + OFF_RF;
    float* WF = ws + OFF_WF;
    float* KF = ws + OFF_KF;
    float* VF = ws + OFF_VF;
    float* AF = ws + OFF_AF;
    float* BF = ws + OFF_BF;
    float* Y  = ws + OFF_Y;

    float* out = (float*)d_out;
    float* out0  = out;                 // (1,256,4096)
    float* xlast = out + 1048576;       // (1,4096)
    float* Sfin  = out + 1052672;       // (1,32,128,128)
    float* vfout = out + 1576960;       // (1,256,4096)
    float* xres  = out + 2625536;       // (1,256,4096)

    // independent: v_first passthrough (LAYER_ID==1)
    hipMemcpyAsync(vfout, vfirst, (size_t)1048576 * 4, hipMemcpyDeviceToDevice, stream);

    rmsnorm_k<<<T_, 256, 0, stream>>>(x_in, ln1, X, xlast);

    gemm_bf16<0><<<dim3(2, 64), 256, 0, stream>>>(X, HN_, R_, HN_, Rb, nullptr, RRAW, HN_, 256, 4096, 4096);
    gemm_bf16<0><<<dim3(2, 16), 256, 0, stream>>>(X, HN_, K_, HN_, Kb, nullptr, KRAW, 1024, 256, 1024, 4096);
    gemm_bf16<0><<<dim3(2, 16), 256, 0, stream>>>(X, HN_, V_, HN_, Vb, nullptr, VRAW, 1024, 256, 1024, 4096);

    lora1_k<<<T_, 256, 0, stream>>>(X, w1, a1, v1, g1, TCAT);

    gemm_bf16<1><<<dim3(2, 64), 256, 0, stream>>>(TCAT + 0,   288, w2, HN_, w0, nullptr, WPRE, HN_, 256, 4096, 64);
    gemm_bf16<1><<<dim3(2, 64), 256, 0, stream>>>(TCAT + 64,  288, a2, HN_, a0, nullptr, APRE, HN_, 256, 4096, 64);
    gemm_bf16<1><<<dim3(2, 64), 256, 0, stream>>>(TCAT + 128, 288, v2, HN_, v0, nullptr, VGPRE, HN_, 256, 4096, 32);
    gemm_bf16<1><<<dim3(2, 64), 256, 0, stream>>>(TCAT + 160, 288, g2, HN_, nullptr, nullptr, GARR, HN_, 256, 4096, 128);

    rope_k<<<64, 256, 0, stream>>>(cpos, COST, SINT);

    prep_k<<<T_, 256, 0, stream>>>(RRAW, KRAW, VRAW, WPRE, APRE, VGPRE, vfirst,
                                   COST, SINT, ln_r, ln_k, RF, WF, KF, VF, AF, BF);

    scan_k<<<dim3(8, 32), 256, 0, stream>>>(state, RF, WF, KF, VF, AF, BF, r_k, GARR, Y, Sfin);

    gemm_bf16<0><<<dim3(2, 64), 256, 0, stream>>>(Y, HN_, O_, HN_, nullptr, x_in, xres, HN_, 256, 4096, 4096);

    rmsnorm_k<<<T_, 256, 0, stream>>>(xres, ln2, out0, nullptr);
}

// Round 2
// 1393.419 us; speedup vs baseline: 1.1059x; 1.1059x over previous
//
#include <hip/hip_runtime.h>
#include <cstdint>
#include <cstddef>

#define T_ 256
#define HN_ 4096
#define H_ 32
#define N_ 128

typedef __attribute__((ext_vector_type(8))) short short8;
typedef __attribute__((ext_vector_type(4))) float f32x4;

__device__ __forceinline__ short f2bf(float f) {
    uint32_t u = __builtin_bit_cast(uint32_t, f);
    u = (u + 0x7fffu + ((u >> 16) & 1u)) >> 16;   // RNE f32->bf16
    return (short)u;
}

__device__ __forceinline__ void ld8(float* d, const float* p) {
    float4 lo = *(const float4*)p, hi = *(const float4*)(p + 4);
    d[0] = lo.x; d[1] = lo.y; d[2] = lo.z; d[3] = lo.w;
    d[4] = hi.x; d[5] = hi.y; d[6] = hi.z; d[7] = hi.w;
}

__device__ __forceinline__ float sigm(float x) { return 1.f / (1.f + expf(-x)); }
__device__ __forceinline__ float splus(float x) { return (x > 20.f) ? x : log1pf(expf(x)); }

// ---------------- RMSNorm over 4096 (t5 style) ----------------
__global__ __launch_bounds__(256) void rmsnorm_k(const float* __restrict__ in,
                                                 const float* __restrict__ w,
                                                 float* __restrict__ out,
                                                 float* __restrict__ lastrow) {
    int t = blockIdx.x, tid = threadIdx.x;
    const float4* in4 = (const float4*)(in + (size_t)t * HN_);
    const float4* w4 = (const float4*)w;
    float4 v[4]; float ss = 0.f;
#pragma unroll
    for (int q = 0; q < 4; q++) {
        v[q] = in4[q * 256 + tid];
        ss += v[q].x * v[q].x + v[q].y * v[q].y + v[q].z * v[q].z + v[q].w * v[q].w;
    }
#pragma unroll
    for (int o = 32; o; o >>= 1) ss += __shfl_down(ss, o);
    __shared__ float red[4];
    if ((tid & 63) == 0) red[tid >> 6] = ss;
    __syncthreads();
    float tot = red[0] + red[1] + red[2] + red[3];
    float sc = rsqrtf(tot * (1.f / HN_) + 1e-6f);
    float4* o4 = (float4*)(out + (size_t)t * HN_);
#pragma unroll
    for (int q = 0; q < 4; q++) {
        float4 wv = w4[q * 256 + tid];
        float4 r;
        r.x = wv.x * v[q].x * sc; r.y = wv.y * v[q].y * sc;
        r.z = wv.z * v[q].z * sc; r.w = wv.w * v[q].w * sc;
        o4[q * 256 + tid] = r;
        if (lastrow != nullptr && t == T_ - 1) ((float4*)lastrow)[q * 256 + tid] = r;
    }
}

// ---------------- bf16 MFMA GEMM: C[m][n] = sum_k A[m][k]*B(k,n) (+bias +resid) ----
// BMAJOR==0: B stored as W[n*ldb + k] (k-contiguous rows = TN)
// BMAJOR==1: B stored as W[k*ldb + n] (n-contiguous rows = NN)
// N may be a non-multiple of 64 as long as N % 16 == 0 (per-fragment guard).
template <int BMAJOR>
__global__ __launch_bounds__(256) void gemm_bf16(
    const float* __restrict__ A, int lda,
    const float* __restrict__ B, int ldb,
    const float* __restrict__ bias,
    const float* __restrict__ resid,
    float* __restrict__ C, int ldc,
    int M, int N, int K) {
    const int tid = threadIdx.x;
    const int wid = tid >> 6;
    const int l = tid & 63;
    const int ar = l & 15;
    const int ak = (l >> 4) * 8;
    const int wm = wid >> 1, wn = wid & 1;
    const int mBase = blockIdx.x * 128 + wm * 64;
    const int nBase = blockIdx.y * 64 + wn * 32;

    f32x4 acc[4][2];
#pragma unroll
    for (int i = 0; i < 4; i++)
#pragma unroll
        for (int j = 0; j < 2; j++) acc[i][j] = f32x4{0.f, 0.f, 0.f, 0.f};

    for (int k0 = 0; k0 < K; k0 += 32) {
        short8 af[4];
#pragma unroll
        for (int i = 0; i < 4; i++) {
            const float* p = A + (size_t)(mBase + i * 16 + ar) * lda + (k0 + ak);
            float4 lo = *(const float4*)p, hi = *(const float4*)(p + 4);
            short8 v;
            v[0] = f2bf(lo.x); v[1] = f2bf(lo.y); v[2] = f2bf(lo.z); v[3] = f2bf(lo.w);
            v[4] = f2bf(hi.x); v[5] = f2bf(hi.y); v[6] = f2bf(hi.z); v[7] = f2bf(hi.w);
            af[i] = v;
        }
        short8 bfr[2];
#pragma unroll
        for (int j = 0; j < 2; j++) {
            int col = nBase + j * 16 + ar;
            short8 v;
            if (nBase + j * 16 < N) {        // wave-uniform (N % 16 == 0)
                if (BMAJOR == 0) {
                    const float* p = B + (size_t)col * ldb + (k0 + ak);
                    float4 lo = *(const float4*)p, hi = *(const float4*)(p + 4);
                    v[0] = f2bf(lo.x); v[1] = f2bf(lo.y); v[2] = f2bf(lo.z); v[3] = f2bf(lo.w);
                    v[4] = f2bf(hi.x); v[5] = f2bf(hi.y); v[6] = f2bf(hi.z); v[7] = f2bf(hi.w);
                } else {
                    const float* p = B + (size_t)(k0 + ak) * ldb + col;
#pragma unroll
                    for (int e = 0; e < 8; e++) v[e] = f2bf(p[(size_t)e * ldb]);
                }
            } else {
#pragma unroll
                for (int e = 0; e < 8; e++) v[e] = 0;
            }
            bfr[j] = v;
        }
#pragma unroll
        for (int i = 0; i < 4; i++)
#pragma unroll
            for (int j = 0; j < 2; j++)
                acc[i][j] = __builtin_amdgcn_mfma_f32_16x16x32_bf16(af[i], bfr[j], acc[i][j], 0, 0, 0);
    }

    const int rl = (l >> 4) * 4;
    const int cl = l & 15;
#pragma unroll
    for (int i = 0; i < 4; i++) {
#pragma unroll
        for (int j = 0; j < 2; j++) {
            int col = nBase + j * 16 + cl;
            if (col < N) {
                float bv = bias ? bias[col] : 0.f;
#pragma unroll
                for (int e = 0; e < 4; e++) {
                    int row = mBase + i * 16 + rl + e;
                    float v = acc[i][j][e] + bv;
                    if (resid) v += resid[(size_t)row * ldc + col];
                    C[(size_t)row * ldc + col] = v;
                }
            }
        }
    }
}

// ---------------- transpose+concat LoRA-A weights -> WT[288][4096] (f32) ----------
__global__ __launch_bounds__(256) void wcat_t_k(const float* __restrict__ w1p,
                                                const float* __restrict__ a1p,
                                                const float* __restrict__ v1p,
                                                const float* __restrict__ g1p,
                                                float* __restrict__ WT) {
    int n = blockIdx.x;   // 288
    const float* src; int ldw, nn;
    if (n < 64)       { src = w1p; ldw = 64;  nn = n; }
    else if (n < 128) { src = a1p; ldw = 64;  nn = n - 64; }
    else if (n < 160) { src = v1p; ldw = 32;  nn = n - 128; }
    else              { src = g1p; ldw = 128; nn = n - 160; }
    float* dst = WT + (size_t)n * HN_;
    for (int k = threadIdx.x; k < HN_; k += 256)
        dst[k] = src[(size_t)k * ldw + nn];
}

// ---------------- activations on TCAT [256][288]: tanh cols 0-63, sigm 160-287 ----
__global__ __launch_bounds__(256) void act_k(float* __restrict__ tcat) {
    int idx = blockIdx.x * 256 + threadIdx.x;   // 73728 total
    int c = idx % 288;
    float v = tcat[idx];
    if (c < 64) v = tanhf(v);
    else if (c >= 160) v = sigm(v);
    tcat[idx] = v;
}

// ---------------- RoPE cos/sin table [T][64] ----------------
__global__ void rope_k(const int* __restrict__ cpos, float* __restrict__ cosT,
                       float* __restrict__ sinT) {
    int idx = blockIdx.x * 256 + threadIdx.x;   // 16384 total
    int t = idx >> 6, f = idx & 63;
    float pos = (float)cpos[0] + (float)t;
    float mix = fminf(fmaxf(pos * (1.f / 4096.f), 0.f), 1.f);
    float e = (float)f * (1.f / 64.f);
    float inv_s = exp2f(-13.287712379549449f * e);                         // 10000^-e
    float inv_l = exp2f(-13.287712379549449f - 3.321928094887362f * e);    // 1/(10000*10^e)
    float fr = pos * ((1.f - mix) * inv_s + mix * inv_l);
    cosT[idx] = cosf(fr);
    sinT[idx] = sinf(fr);
}

// ---------------- elementwise prep: per-head rmsnorm + rope + gates -> scan layout ----
__global__ __launch_bounds__(256) void prep_k(
    const float* __restrict__ r_raw, const float* __restrict__ k_raw,
    const float* __restrict__ v_raw, const float* __restrict__ wpre,
    const float* __restrict__ apre, const float* __restrict__ vgpre,
    const float* __restrict__ vfirst, const float* __restrict__ cosT,
    const float* __restrict__ sinT, const float* __restrict__ lnr,
    const float* __restrict__ lnk,
    float* __restrict__ rf, float* __restrict__ wf, float* __restrict__ kf,
    float* __restrict__ vf, float* __restrict__ raf, float* __restrict__ rbf) {
    int t = blockIdx.x, tid = threadIdx.x;
    int w = tid >> 6, lane = tid & 63;
    float c = cosT[t * 64 + lane], s = sinT[t * 64 + lane];
    float lr0 = lnr[lane], lr1 = lnr[lane + 64];
    float lk0 = lnk[lane], lk1 = lnk[lane + 64];
    for (int hb = 0; hb < 8; hb++) {
        int h = hb * 4 + w;
        int kv = h >> 2;
        // ---- r: per-head rmsnorm + rope
        float r0 = r_raw[(size_t)t * HN_ + h * 128 + lane];
        float r1 = r_raw[(size_t)t * HN_ + h * 128 + 64 + lane];
        float ssum = r0 * r0 + r1 * r1;
#pragma unroll
        for (int o = 32; o; o >>= 1) ssum += __shfl_xor(ssum, o);
        float sc = rsqrtf(ssum * (1.f / 128.f) + 1e-6f);
        float rn0 = lr0 * r0 * sc, rn1 = lr1 * r1 * sc;
        float rr0 = rn0 * c - rn1 * s;
        float rr1 = rn1 * c + rn0 * s;
        // ---- k: per-kv-head rmsnorm + rope (redundant across the 4 repeats, fine)
        float k0 = k_raw[(size_t)t * 1024 + kv * 128 + lane];
        float k1 = k_raw[(size_t)t * 1024 + kv * 128 + 64 + lane];
        float ks = k0 * k0 + k1 * k1;
#pragma unroll
        for (int o = 32; o; o >>= 1) ks += __shfl_xor(ks, o);
        float ksc = rsqrtf(ks * (1.f / 128.f) + 1e-6f);
        float kn0 = lk0 * k0 * ksc, kn1 = lk1 * k1 * ksc;
        float kr0 = kn0 * c - kn1 * s;
        float kr1 = kn1 * c + kn0 * s;
        // ---- kk = k / max(||k||, 1e-12)
        float nr = kr0 * kr0 + kr1 * kr1;
#pragma unroll
        for (int o = 32; o; o >>= 1) nr += __shfl_xor(nr, o);
        float inv = 1.f / fmaxf(sqrtf(nr), 1e-12f);
        float kk0 = kr0 * inv, kk1 = kr1 * inv;
        // ---- per-channel gates
        int c0 = h * 128 + lane, c1 = c0 + 64;
        size_t tb = (size_t)t * HN_;
        size_t ob = (size_t)h * (T_ * 128) + (size_t)t * 128 + lane;

        float wv0 = -splus(-wpre[tb + c0]) - 0.5f;
        float wv1 = -splus(-wpre[tb + c1]) - 0.5f;
        float dec0 = expf(-expf(wv0));
        float dec1 = expf(-expf(wv1));
        float av0 = sigm(apre[tb + c0]);
        float av1 = sigm(apre[tb + c1]);
        float vg0 = sigm(vgpre[tb + c0]);
        float vg1 = sigm(vgpre[tb + c1]);
        float vraw0 = v_raw[(size_t)t * 1024 + kv * 128 + lane];
        float vraw1 = v_raw[(size_t)t * 1024 + kv * 128 + 64 + lane];
        float vf0 = vraw0 + (vfirst[tb + c0] - vraw0) * vg0;
        float vf1 = vraw1 + (vfirst[tb + c1] - vraw1) * vg1;

        rf[ob] = rr0;            rf[ob + 64] = rr1;
        wf[ob] = dec0;           wf[ob + 64] = dec1;
        kf[ob] = kr0 * (1.f - wv0 + av0);
        kf[ob + 64] = kr1 * (1.f - wv1 + av1);
        vf[ob] = vf0;            vf[ob + 64] = vf1;
        raf[ob] = -kk0;          raf[ob + 64] = -kk1;
        rbf[ob] = kk0 * av0;     rbf[ob + 64] = kk1 * av1;
    }
}

// ---------------- sequential scan: 256 blocks = (8 row-splits x 32 heads) ----------
__global__ __launch_bounds__(256) void scan_k(
    const float* __restrict__ state_in,
    const float* __restrict__ rf, const float* __restrict__ wf,
    const float* __restrict__ kf, const float* __restrict__ vf,
    const float* __restrict__ raf, const float* __restrict__ rbf,
    const float* __restrict__ rk, const float* __restrict__ g,
    float* __restrict__ y, float* __restrict__ Sout) {
    int sp = blockIdx.x, h = blockIdx.y;
    int tid = threadIdx.x;
    int il = tid >> 4, jq = tid & 15;
    int i = sp * 16 + il, j0 = jq * 8;

    float S[8];
    ld8(S, state_in + ((size_t)h * 128 + i) * 128 + j0);
    float rk8[8];
    ld8(rk8, rk + h * 128 + j0);
    size_t hb = (size_t)h * (T_ * 128);

    struct V8 { float a[8], b[8], k[8], w[8], r[8]; float vi; };
    V8 bufA, bufB;
    auto LOAD = [&](V8& d, int t) {
        size_t base = hb + (size_t)t * 128;
        ld8(d.a, raf + base + j0);
        ld8(d.b, rbf + base + j0);
        ld8(d.k, kf + base + j0);
        ld8(d.w, wf + base + j0);
        ld8(d.r, rf + base + j0);
        d.vi = vf[base + i];
    };
    auto STEP = [&](V8& u, int t) {
        float sa = 0.f;
#pragma unroll
        for (int e = 0; e < 8; e++) sa = fmaf(S[e], u.a[e], sa);
        sa += __shfl_xor(sa, 1); sa += __shfl_xor(sa, 2);
        sa += __shfl_xor(sa, 4); sa += __shfl_xor(sa, 8);
        float od = 0.f, bd = 0.f;
#pragma unroll
        for (int e = 0; e < 8; e++) {
            S[e] = fmaf(u.vi, u.k[e], fmaf(sa, u.b[e], S[e] * u.w[e]));
            od = fmaf(S[e], u.r[e], od);
            bd = fmaf(u.r[e] * u.k[e], rk8[e], bd);
        }
        od += __shfl_xor(od, 1); od += __shfl_xor(od, 2);
        od += __shfl_xor(od, 4); od += __shfl_xor(od, 8);
        bd += __shfl_xor(bd, 1); bd += __shfl_xor(bd, 2);
        bd += __shfl_xor(bd, 4); bd += __shfl_xor(bd, 8);
        if (jq == 0) {
            size_t oi = (size_t)t * HN_ + h * 128 + i;
            y[oi] = (od * 0.08838834764831845f + bd * u.vi) * g[oi];
        }
    };

    LOAD(bufA, 0);
    for (int t = 0; t < T_; t += 2) {
        LOAD(bufB, t + 1);
        STEP(bufA, t);
        if (t + 2 < T_) LOAD(bufA, t + 2);
        STEP(bufB, t + 1);
    }
    float* p = Sout + ((size_t)h * 128 + i) * 128 + j0;
    *(float4*)p = make_float4(S[0], S[1], S[2], S[3]);
    *(float4*)(p + 4) = make_float4(S[4], S[5], S[6], S[7]);
}

// =====================================================================================
extern "C" void kernel_launch(void* const* d_in, const int* in_sizes, int n_in,
                              void* d_out, int out_size, void* d_ws, size_t ws_size,
                              hipStream_t stream) {
    const float* x_in   = (const float*)d_in[0];
    const float* vfirst = (const float*)d_in[1];
    const float* state  = (const float*)d_in[2];
    const int*   cpos   = (const int*)d_in[3];
    const float* w0 = (const float*)d_in[4];
    const float* w1 = (const float*)d_in[5];
    const float* w2 = (const float*)d_in[6];
    const float* a0 = (const float*)d_in[7];
    const float* a1 = (const float*)d_in[8];
    const float* a2 = (const float*)d_in[9];
    const float* v0 = (const float*)d_in[10];
    const float* v1 = (const float*)d_in[11];
    const float* v2 = (const float*)d_in[12];
    const float* g1 = (const float*)d_in[13];
    const float* g2 = (const float*)d_in[14];
    const float* r_k = (const float*)d_in[15];
    const float* R_ = (const float*)d_in[16];
    const float* K_ = (const float*)d_in[17];
    const float* V_ = (const float*)d_in[18];
    const float* O_ = (const float*)d_in[19];
    const float* Rb = (const float*)d_in[20];
    const float* Kb = (const float*)d_in[21];
    const float* Vb = (const float*)d_in[22];
    const float* ln_r = (const float*)d_in[23];
    const float* ln_k = (const float*)d_in[24];
    const float* ln1 = (const float*)d_in[25];
    const float* ln2 = (const float*)d_in[26];

    float* ws = (float*)d_ws;
    constexpr size_t OFF_X    = 0;
    constexpr size_t OFF_RRAW = 1048576;
    constexpr size_t OFF_KRAW = 2097152;
    constexpr size_t OFF_VRAW = 2359296;
    constexpr size_t OFF_TCAT = 2621440;
    constexpr size_t OFF_WPRE = 2695168;
    constexpr size_t OFF_APRE = 3743744;
    constexpr size_t OFF_VGPRE= 4792320;
    constexpr size_t OFF_G    = 5840896;
    constexpr size_t OFF_COS  = 6889472;
    constexpr size_t OFF_SIN  = 6905856;
    constexpr size_t OFF_RF   = 6922240;   // also reused earlier as WT (288*4096)
    constexpr size_t OFF_WF   = 7970816;
    constexpr size_t OFF_KF   = 9019392;
    constexpr size_t OFF_VF   = 10067968;
    constexpr size_t OFF_AF   = 11116544;
    constexpr size_t OFF_BF   = 12165120;
    constexpr size_t OFF_Y    = 13213696;

    float* X    = ws + OFF_X;
    float* RRAW = ws + OFF_RRAW;
    float* KRAW = ws + OFF_KRAW;
    float* VRAW = ws + OFF_VRAW;
    float* TCAT = ws + OFF_TCAT;
    float* WPRE = ws + OFF_WPRE;
    float* APRE = ws + OFF_APRE;
    float* VGPRE= ws + OFF_VGPRE;
    float* GARR = ws + OFF_G;
    float* COST = ws + OFF_COS;
    float* SINT = ws + OFF_SIN;
    float* RF = ws + OFF_RF;
    float* WF = ws + OFF_WF;
    float* KF = ws + OFF_KF;
    float* VF = ws + OFF_VF;
    float* AF = ws + OFF_AF;
    float* BF = ws + OFF_BF;
    float* Y  = ws + OFF_Y;
    float* WT = ws + OFF_RF;   // dead region until prep_k writes RF

    float* out = (float*)d_out;
    float* out0  = out;                 // (1,256,4096)
    float* xlast = out + 1048576;       // (1,4096)
    float* Sfin  = out + 1052672;       // (1,32,128,128)
    float* vfout = out + 1576960;       // (1,256,4096)
    float* xres  = out + 2625536;       // (1,256,4096)

    // independent: v_first passthrough (LAYER_ID==1)
    hipMemcpyAsync(vfout, vfirst, (size_t)1048576 * 4, hipMemcpyDeviceToDevice, stream);

    rmsnorm_k<<<T_, 256, 0, stream>>>(x_in, ln1, X, xlast);

    gemm_bf16<0><<<dim3(2, 64), 256, 0, stream>>>(X, HN_, R_, HN_, Rb, nullptr, RRAW, HN_, 256, 4096, 4096);
    gemm_bf16<0><<<dim3(2, 16), 256, 0, stream>>>(X, HN_, K_, HN_, Kb, nullptr, KRAW, 1024, 256, 1024, 4096);
    gemm_bf16<0><<<dim3(2, 16), 256, 0, stream>>>(X, HN_, V_, HN_, Vb, nullptr, VRAW, 1024, 256, 1024, 4096);

    // ---- LoRA stage-1 as MFMA GEMM: WT = concat-transpose, TCAT = X @ WT^T, act ----
    wcat_t_k<<<288, 256, 0, stream>>>(w1, a1, v1, g1, WT);
    gemm_bf16<0><<<dim3(2, 5), 256, 0, stream>>>(X, HN_, WT, HN_, nullptr, nullptr, TCAT, 288, 256, 288, 4096);
    act_k<<<288, 256, 0, stream>>>(TCAT);

    gemm_bf16<1><<<dim3(2, 64), 256, 0, stream>>>(TCAT + 0,   288, w2, HN_, w0, nullptr, WPRE, HN_, 256, 4096, 64);
    gemm_bf16<1><<<dim3(2, 64), 256, 0, stream>>>(TCAT + 64,  288, a2, HN_, a0, nullptr, APRE, HN_, 256, 4096, 64);
    gemm_bf16<1><<<dim3(2, 64), 256, 0, stream>>>(TCAT + 128, 288, v2, HN_, v0, nullptr, VGPRE, HN_, 256, 4096, 32);
    gemm_bf16<1><<<dim3(2, 64), 256, 0, stream>>>(TCAT + 160, 288, g2, HN_, nullptr, nullptr, GARR, HN_, 256, 4096, 128);

    rope_k<<<64, 256, 0, stream>>>(cpos, COST, SINT);

    prep_k<<<T_, 256, 0, stream>>>(RRAW, KRAW, VRAW, WPRE, APRE, VGPRE, vfirst,
                                   COST, SINT, ln_r, ln_k, RF, WF, KF, VF, AF, BF);

    scan_k<<<dim3(8, 32), 256, 0, stream>>>(state, RF, WF, KF, VF, AF, BF, r_k, GARR, Y, Sfin);

    gemm_bf16<0><<<dim3(2, 64), 256, 0, stream>>>(Y, HN_, O_, HN_, nullptr, x_in, xres, HN_, 256, 4096, 4096);

    rmsnorm_k<<<T_, 256, 0, stream>>>(xres, ln2, out0, nullptr);
}

// Round 4
// 549.005 us; speedup vs baseline: 2.8068x; 2.5381x over previous
//
#include <hip/hip_runtime.h>
#include <cstdint>
#include <cstddef>

#define T_ 256
#define HN_ 4096
#define H_ 32
#define N_ 128
#define SR_ 6464   // COMB row stride (4096 R + 1024 K + 1024 V + 320 T)

typedef __attribute__((ext_vector_type(8))) short short8;
typedef __attribute__((ext_vector_type(4))) float f32x4;

__device__ __forceinline__ short f2bf(float f) {
    uint32_t u = __builtin_bit_cast(uint32_t, f);
    u = (u + 0x7fffu + ((u >> 16) & 1u)) >> 16;   // RNE f32->bf16
    return (short)u;
}
__device__ __forceinline__ short f2bfc(float f) {  // cheap round-half-up
    return (short)((__builtin_bit_cast(uint32_t, f) + 0x8000u) >> 16);
}
__device__ __forceinline__ short8 cvt8(const float* p) {
    float4 lo = *(const float4*)p, hi = *(const float4*)(p + 4);
    short8 v;
    v[0] = f2bfc(lo.x); v[1] = f2bfc(lo.y); v[2] = f2bfc(lo.z); v[3] = f2bfc(lo.w);
    v[4] = f2bfc(hi.x); v[5] = f2bfc(hi.y); v[6] = f2bfc(hi.z); v[7] = f2bfc(hi.w);
    return v;
}
__device__ __forceinline__ f32x4 mfma16(short8 a, short8 b, f32x4 c) {
    return __builtin_amdgcn_mfma_f32_16x16x32_bf16(a, b, c, 0, 0, 0);
}
__device__ __forceinline__ void ld8(float* d, const float* p) {
    float4 lo = *(const float4*)p, hi = *(const float4*)(p + 4);
    d[0] = lo.x; d[1] = lo.y; d[2] = lo.z; d[3] = lo.w;
    d[4] = hi.x; d[5] = hi.y; d[6] = hi.z; d[7] = hi.w;
}
__device__ __forceinline__ float sigm(float x) { return 1.f / (1.f + expf(-x)); }
__device__ __forceinline__ float splus(float x) { return (x > 20.f) ? x : log1pf(expf(x)); }

// ---------------- RMSNorm over 4096; optional f32 out, bf16 out, lastrow ----------
__global__ __launch_bounds__(256) void rmsnorm_k(const float* __restrict__ in,
                                                 const float* __restrict__ w,
                                                 float* __restrict__ outF,
                                                 ushort* __restrict__ outB,
                                                 float* __restrict__ lastrow) {
    int t = blockIdx.x, tid = threadIdx.x;
    const float4* in4 = (const float4*)(in + (size_t)t * HN_);
    const float4* w4 = (const float4*)w;
    float4 v[4]; float ss = 0.f;
#pragma unroll
    for (int q = 0; q < 4; q++) {
        v[q] = in4[q * 256 + tid];
        ss += v[q].x * v[q].x + v[q].y * v[q].y + v[q].z * v[q].z + v[q].w * v[q].w;
    }
#pragma unroll
    for (int o = 32; o; o >>= 1) ss += __shfl_down(ss, o);
    __shared__ float red[4];
    if ((tid & 63) == 0) red[tid >> 6] = ss;
    __syncthreads();
    float tot = red[0] + red[1] + red[2] + red[3];
    float sc = rsqrtf(tot * (1.f / HN_) + 1e-6f);
#pragma unroll
    for (int q = 0; q < 4; q++) {
        float4 wv = w4[q * 256 + tid];
        float4 r;
        r.x = wv.x * v[q].x * sc; r.y = wv.y * v[q].y * sc;
        r.z = wv.z * v[q].z * sc; r.w = wv.w * v[q].w * sc;
        int idx = q * 256 + tid;
        if (outF) ((float4*)(outF + (size_t)t * HN_))[idx] = r;
        if (outB) {
            ushort4 b;
            b.x = (ushort)f2bf(r.x); b.y = (ushort)f2bf(r.y);
            b.z = (ushort)f2bf(r.z); b.w = (ushort)f2bf(r.w);
            ((ushort4*)(outB + (size_t)t * HN_))[idx] = b;
        }
        if (lastrow && t == T_ - 1) ((float4*)lastrow)[idx] = r;
    }
}

// ---------------- fused R/K/V/LoRA1 split-K GEMM, atomic epilogue into COMB ------
// BM=256 (all rows), BN=32 per block, 8 waves (512 thr), grid (202, KSPLIT)
__global__ __launch_bounds__(512) void gemm_rkvt(
    const ushort* __restrict__ A,          // XB [256][4096] bf16
    const float* __restrict__ Rw, const float* __restrict__ Kw,
    const float* __restrict__ Vw, const float* __restrict__ WT,
    float* __restrict__ COMB, int kchunk) {
    const int tid = threadIdx.x, wid = tid >> 6, l = tid & 63;
    const int ar = l & 15, ak = (l >> 4) * 8;
    const int mBase = wid * 32;
    const int nB = blockIdx.x * 32;
    const int kbeg = blockIdx.y * kchunk;

    const float* Bp; int brow;
    if (nB < 4096)      { Bp = Rw; brow = nB; }
    else if (nB < 5120) { Bp = Kw; brow = nB - 4096; }
    else if (nB < 6144) { Bp = Vw; brow = nB - 5120; }
    else                { Bp = WT; brow = nB - 6144; }

    f32x4 acc[2][2];
#pragma unroll
    for (int i = 0; i < 2; i++)
#pragma unroll
        for (int j = 0; j < 2; j++) acc[i][j] = f32x4{0.f, 0.f, 0.f, 0.f};

    const ushort* pA0 = A + (size_t)(mBase + ar) * 4096 + kbeg + ak;
    const ushort* pA1 = pA0 + (size_t)16 * 4096;
    const float* pB0 = Bp + (size_t)(brow + ar) * 4096 + kbeg + ak;
    const float* pB1 = pB0 + (size_t)16 * 4096;

    for (int ks = 0; ks < kchunk; ks += 32) {
        short8 a0 = *(const short8*)pA0; pA0 += 32;
        short8 a1 = *(const short8*)pA1; pA1 += 32;
        short8 b0 = cvt8(pB0); pB0 += 32;
        short8 b1 = cvt8(pB1); pB1 += 32;
        acc[0][0] = mfma16(a0, b0, acc[0][0]);
        acc[0][1] = mfma16(a0, b1, acc[0][1]);
        acc[1][0] = mfma16(a1, b0, acc[1][0]);
        acc[1][1] = mfma16(a1, b1, acc[1][1]);
    }
    const int rl = (l >> 4) * 4, cl = l & 15;
#pragma unroll
    for (int mf = 0; mf < 2; mf++)
#pragma unroll
        for (int nf = 0; nf < 2; nf++)
#pragma unroll
            for (int e = 0; e < 4; e++)
                unsafeAtomicAdd(&COMB[(size_t)(mBase + mf * 16 + rl + e) * SR_ + nB + nf * 16 + cl],
                                acc[mf][nf][e]);
}

// ---------------- O GEMM: xres += YB @ O^T (atomic, split-K) ---------------------
__global__ __launch_bounds__(512) void gemm_o(
    const ushort* __restrict__ A,          // YB [256][4096] bf16
    const float* __restrict__ B,           // O_ [4096][4096] TN
    float* __restrict__ C, int kchunk) {
    const int tid = threadIdx.x, wid = tid >> 6, l = tid & 63;
    const int ar = l & 15, ak = (l >> 4) * 8;
    const int mBase = wid * 32;
    const int nB = blockIdx.x * 32;
    const int kbeg = blockIdx.y * kchunk;

    f32x4 acc[2][2];
#pragma unroll
    for (int i = 0; i < 2; i++)
#pragma unroll
        for (int j = 0; j < 2; j++) acc[i][j] = f32x4{0.f, 0.f, 0.f, 0.f};

    const ushort* pA0 = A + (size_t)(mBase + ar) * 4096 + kbeg + ak;
    const ushort* pA1 = pA0 + (size_t)16 * 4096;
    const float* pB0 = B + (size_t)(nB + ar) * 4096 + kbeg + ak;
    const float* pB1 = pB0 + (size_t)16 * 4096;

    for (int ks = 0; ks < kchunk; ks += 32) {
        short8 a0 = *(const short8*)pA0; pA0 += 32;
        short8 a1 = *(const short8*)pA1; pA1 += 32;
        short8 b0 = cvt8(pB0); pB0 += 32;
        short8 b1 = cvt8(pB1); pB1 += 32;
        acc[0][0] = mfma16(a0, b0, acc[0][0]);
        acc[0][1] = mfma16(a0, b1, acc[0][1]);
        acc[1][0] = mfma16(a1, b0, acc[1][0]);
        acc[1][1] = mfma16(a1, b1, acc[1][1]);
    }
    const int rl = (l >> 4) * 4, cl = l & 15;
#pragma unroll
    for (int mf = 0; mf < 2; mf++)
#pragma unroll
        for (int nf = 0; nf < 2; nf++)
#pragma unroll
            for (int e = 0; e < 4; e++)
                unsafeAtomicAdd(&C[(size_t)(mBase + mf * 16 + rl + e) * 4096 + nB + nf * 16 + cl],
                                acc[mf][nf][e]);
}

// ---------------- fused stage-2 LoRA GEMMs (4 segments via blockIdx.y) -----------
__global__ __launch_bounds__(512) void gemm_s2(
    const ushort* __restrict__ TCB,        // [256][320] bf16
    const float* __restrict__ w2, const float* __restrict__ a2,
    const float* __restrict__ v2, const float* __restrict__ g2,
    const float* __restrict__ w0, const float* __restrict__ a0,
    const float* __restrict__ v0,
    float* __restrict__ WPRE, float* __restrict__ APRE,
    float* __restrict__ VGPRE, float* __restrict__ GARR) {
    const int z = blockIdx.y;
    int Aoff, K; const float* B; const float* bias; float* out;
    if (z == 0)      { Aoff = 0;   K = 64;  B = w2; bias = w0;      out = WPRE; }
    else if (z == 1) { Aoff = 64;  K = 64;  B = a2; bias = a0;      out = APRE; }
    else if (z == 2) { Aoff = 128; K = 32;  B = v2; bias = v0;      out = VGPRE; }
    else             { Aoff = 160; K = 128; B = g2; bias = nullptr; out = GARR; }

    const int tid = threadIdx.x, wid = tid >> 6, l = tid & 63;
    const int ar = l & 15, ak = (l >> 4) * 8;
    const int mBase = wid * 32;
    const int nB = blockIdx.x * 32;

    f32x4 acc[2][2];
#pragma unroll
    for (int i = 0; i < 2; i++)
#pragma unroll
        for (int j = 0; j < 2; j++) acc[i][j] = f32x4{0.f, 0.f, 0.f, 0.f};

    for (int k0 = 0; k0 < K; k0 += 32) {
        const ushort* pA = TCB + (size_t)(mBase + ar) * 320 + Aoff + k0 + ak;
        short8 av0 = *(const short8*)pA;
        short8 av1 = *(const short8*)(pA + (size_t)16 * 320);
        short8 bv0, bv1;
#pragma unroll
        for (int e = 0; e < 8; e++) {
            bv0[e] = f2bfc(B[(size_t)(k0 + ak + e) * 4096 + nB + ar]);
            bv1[e] = f2bfc(B[(size_t)(k0 + ak + e) * 4096 + nB + 16 + ar]);
        }
        acc[0][0] = mfma16(av0, bv0, acc[0][0]);
        acc[0][1] = mfma16(av0, bv1, acc[0][1]);
        acc[1][0] = mfma16(av1, bv0, acc[1][0]);
        acc[1][1] = mfma16(av1, bv1, acc[1][1]);
    }
    const int rl = (l >> 4) * 4, cl = l & 15;
#pragma unroll
    for (int mf = 0; mf < 2; mf++)
#pragma unroll
        for (int nf = 0; nf < 2; nf++) {
            int col = nB + nf * 16 + cl;
            float bv = bias ? bias[col] : 0.f;
#pragma unroll
            for (int e = 0; e < 4; e++)
                out[(size_t)(mBase + mf * 16 + rl + e) * 4096 + col] = acc[mf][nf][e] + bv;
        }
}

// ---------------- LoRA-A concat-transpose via LDS tiles -> WT[320][4096] ---------
__global__ __launch_bounds__(256) void wcat2_k(const float* __restrict__ w1p,
                                               const float* __restrict__ a1p,
                                               const float* __restrict__ v1p,
                                               const float* __restrict__ g1p,
                                               float* __restrict__ WT) {
    const int kb = blockIdx.x * 64, tile = blockIdx.y;
    const float* src; int ldw, jo, nb, W;
    if (tile == 0)      { src = w1p; ldw = 64;  jo = 0;  nb = 0;   W = 64; }
    else if (tile == 1) { src = a1p; ldw = 64;  jo = 0;  nb = 64;  W = 64; }
    else if (tile == 2) { src = v1p; ldw = 32;  jo = 0;  nb = 128; W = 32; }
    else if (tile == 3) { src = g1p; ldw = 128; jo = 0;  nb = 160; W = 64; }
    else                { src = g1p; ldw = 128; jo = 64; nb = 224; W = 64; }
    __shared__ float lds[64][65];
    const int ti = threadIdx.x & 63, wi = threadIdx.x >> 6;
    if (ti < W)
        for (int i = wi; i < 64; i += 4)
            lds[i][ti] = src[(size_t)(kb + i) * ldw + jo + ti];
    __syncthreads();
    for (int i2 = wi; i2 < W; i2 += 4)
        WT[(size_t)(nb + i2) * 4096 + kb + ti] = lds[ti][i2];
}

// ---------------- init COMB rows with biases (atomic GEMM accumulates on top) ----
__global__ __launch_bounds__(256) void init_comb_k(const float* __restrict__ Rb,
                                                   const float* __restrict__ Kb,
                                                   const float* __restrict__ Vb,
                                                   float* __restrict__ COMB) {
    int t = blockIdx.x;
    for (int c = threadIdx.x; c < SR_; c += 256) {
        float b = (c < 4096) ? Rb[c] : (c < 5120) ? Kb[c - 4096]
                : (c < 6144) ? Vb[c - 5120] : 0.f;
        COMB[(size_t)t * SR_ + c] = b;
    }
}

// ---------------- activations on TCAT cols of COMB -> TCB bf16 [256][320] --------
__global__ __launch_bounds__(256) void act_k(const float* __restrict__ COMB,
                                             ushort* __restrict__ TCB) {
    int idx = blockIdx.x * 256 + threadIdx.x;   // 256*288
    if (idx >= 256 * 288) return;
    int t = idx / 288, c = idx % 288;
    float v = COMB[(size_t)t * SR_ + 6144 + c];
    if (c < 64) v = tanhf(v);
    else if (c >= 160) v = sigm(v);
    TCB[t * 320 + c] = (ushort)f2bf(v);
}

// ---------------- RoPE cos/sin table [T][64] ----------------
__global__ void rope_k(const int* __restrict__ cpos, float* __restrict__ cosT,
                       float* __restrict__ sinT) {
    int idx = blockIdx.x * 256 + threadIdx.x;   // 16384 total
    int t = idx >> 6, f = idx & 63;
    float pos = (float)cpos[0] + (float)t;
    float mix = fminf(fmaxf(pos * (1.f / 4096.f), 0.f), 1.f);
    float e = (float)f * (1.f / 64.f);
    float inv_s = exp2f(-13.287712379549449f * e);
    float inv_l = exp2f(-13.287712379549449f - 3.321928094887362f * e);
    float fr = pos * ((1.f - mix) * inv_s + mix * inv_l);
    cosT[idx] = cosf(fr);
    sinT[idx] = sinf(fr);
}

// ---------------- elementwise prep -> scan layout --------------------------------
__global__ __launch_bounds__(256) void prep_k(
    const float* __restrict__ COMB, const float* __restrict__ wpre,
    const float* __restrict__ apre, const float* __restrict__ vgpre,
    const float* __restrict__ vfirst, const float* __restrict__ cosT,
    const float* __restrict__ sinT, const float* __restrict__ lnr,
    const float* __restrict__ lnk,
    float* __restrict__ rf, float* __restrict__ wf, float* __restrict__ kf,
    float* __restrict__ vf, float* __restrict__ raf, float* __restrict__ rbf) {
    int t = blockIdx.x, tid = threadIdx.x;
    int w = tid >> 6, lane = tid & 63;
    float c = cosT[t * 64 + lane], s = sinT[t * 64 + lane];
    float lr0 = lnr[lane], lr1 = lnr[lane + 64];
    float lk0 = lnk[lane], lk1 = lnk[lane + 64];
    const float* r_raw = COMB;
    const float* k_raw = COMB + 4096;
    const float* v_raw = COMB + 5120;
    for (int hb = 0; hb < 8; hb++) {
        int h = hb * 4 + w;
        int kv = h >> 2;
        float r0 = r_raw[(size_t)t * SR_ + h * 128 + lane];
        float r1 = r_raw[(size_t)t * SR_ + h * 128 + 64 + lane];
        float ssum = r0 * r0 + r1 * r1;
#pragma unroll
        for (int o = 32; o; o >>= 1) ssum += __shfl_xor(ssum, o);
        float sc = rsqrtf(ssum * (1.f / 128.f) + 1e-6f);
        float rn0 = lr0 * r0 * sc, rn1 = lr1 * r1 * sc;
        float rr0 = rn0 * c - rn1 * s;
        float rr1 = rn1 * c + rn0 * s;
        float k0 = k_raw[(size_t)t * SR_ + kv * 128 + lane];
        float k1 = k_raw[(size_t)t * SR_ + kv * 128 + 64 + lane];
        float ks = k0 * k0 + k1 * k1;
#pragma unroll
        for (int o = 32; o; o >>= 1) ks += __shfl_xor(ks, o);
        float ksc = rsqrtf(ks * (1.f / 128.f) + 1e-6f);
        float kn0 = lk0 * k0 * ksc, kn1 = lk1 * k1 * ksc;
        float kr0 = kn0 * c - kn1 * s;
        float kr1 = kn1 * c + kn0 * s;
        float nr = kr0 * kr0 + kr1 * kr1;
#pragma unroll
        for (int o = 32; o; o >>= 1) nr += __shfl_xor(nr, o);
        float inv = 1.f / fmaxf(sqrtf(nr), 1e-12f);
        float kk0 = kr0 * inv, kk1 = kr1 * inv;
        int c0 = h * 128 + lane, c1 = c0 + 64;
        size_t tb = (size_t)t * HN_;
        size_t ob = (size_t)h * (T_ * 128) + (size_t)t * 128 + lane;

        float wv0 = -splus(-wpre[tb + c0]) - 0.5f;
        float wv1 = -splus(-wpre[tb + c1]) - 0.5f;
        float dec0 = expf(-expf(wv0));
        float dec1 = expf(-expf(wv1));
        float av0 = sigm(apre[tb + c0]);
        float av1 = sigm(apre[tb + c1]);
        float vg0 = sigm(vgpre[tb + c0]);
        float vg1 = sigm(vgpre[tb + c1]);
        float vraw0 = v_raw[(size_t)t * SR_ + kv * 128 + lane];
        float vraw1 = v_raw[(size_t)t * SR_ + kv * 128 + 64 + lane];
        float vf0 = vraw0 + (vfirst[tb + c0] - vraw0) * vg0;
        float vf1 = vraw1 + (vfirst[tb + c1] - vraw1) * vg1;

        rf[ob] = rr0;            rf[ob + 64] = rr1;
        wf[ob] = dec0;           wf[ob + 64] = dec1;
        kf[ob] = kr0 * (1.f - wv0 + av0);
        kf[ob + 64] = kr1 * (1.f - wv1 + av1);
        vf[ob] = vf0;            vf[ob + 64] = vf1;
        raf[ob] = -kk0;          raf[ob + 64] = -kk1;
        rbf[ob] = kk0 * av0;     rbf[ob + 64] = kk1 * av1;
    }
}

// ---------------- sequential scan: 256 blocks = (8 row-splits x 32 heads) --------
__global__ __launch_bounds__(256) void scan_k(
    const float* __restrict__ state_in,
    const float* __restrict__ rf, const float* __restrict__ wf,
    const float* __restrict__ kf, const float* __restrict__ vf,
    const float* __restrict__ raf, const float* __restrict__ rbf,
    const float* __restrict__ rk, const float* __restrict__ g,
    ushort* __restrict__ yb, float* __restrict__ Sout) {
    int sp = blockIdx.x, h = blockIdx.y;
    int tid = threadIdx.x;
    int il = tid >> 4, jq = tid & 15;
    int i = sp * 16 + il, j0 = jq * 8;

    float S[8];
    ld8(S, state_in + ((size_t)h * 128 + i) * 128 + j0);
    float rk8[8];
    ld8(rk8, rk + h * 128 + j0);
    size_t hb = (size_t)h * (T_ * 128);

    struct V8 { float a[8], b[8], k[8], w[8], r[8]; float vi; };
    V8 bufA, bufB;
    auto LOAD = [&](V8& d, int t) {
        size_t base = hb + (size_t)t * 128;
        ld8(d.a, raf + base + j0);
        ld8(d.b, rbf + base + j0);
        ld8(d.k, kf + base + j0);
        ld8(d.w, wf + base + j0);
        ld8(d.r, rf + base + j0);
        d.vi = vf[base + i];
    };
    auto STEP = [&](V8& u, int t) {
        float sa = 0.f;
#pragma unroll
        for (int e = 0; e < 8; e++) sa = fmaf(S[e], u.a[e], sa);
        sa += __shfl_xor(sa, 1); sa += __shfl_xor(sa, 2);
        sa += __shfl_xor(sa, 4); sa += __shfl_xor(sa, 8);
        float od = 0.f, bd = 0.f;
#pragma unroll
        for (int e = 0; e < 8; e++) {
            S[e] = fmaf(u.vi, u.k[e], fmaf(sa, u.b[e], S[e] * u.w[e]));
            od = fmaf(S[e], u.r[e], od);
            bd = fmaf(u.r[e] * u.k[e], rk8[e], bd);
        }
        od += __shfl_xor(od, 1); od += __shfl_xor(od, 2);
        od += __shfl_xor(od, 4); od += __shfl_xor(od, 8);
        bd += __shfl_xor(bd, 1); bd += __shfl_xor(bd, 2);
        bd += __shfl_xor(bd, 4); bd += __shfl_xor(bd, 8);
        if (jq == 0) {
            size_t oi = (size_t)t * HN_ + h * 128 + i;
            yb[oi] = (ushort)f2bf((od * 0.08838834764831845f + bd * u.vi) * g[oi]);
        }
    };

    LOAD(bufA, 0);
    for (int t = 0; t < T_; t += 2) {
        LOAD(bufB, t + 1);
        STEP(bufA, t);
        if (t + 2 < T_) LOAD(bufA, t + 2);
        STEP(bufB, t + 1);
    }
    float* p = Sout + ((size_t)h * 128 + i) * 128 + j0;
    *(float4*)p = make_float4(S[0], S[1], S[2], S[3]);
    *(float4*)(p + 4) = make_float4(S[4], S[5], S[6], S[7]);
}

// =====================================================================================
extern "C" void kernel_launch(void* const* d_in, const int* in_sizes, int n_in,
                              void* d_out, int out_size, void* d_ws, size_t ws_size,
                              hipStream_t stream) {
    const float* x_in   = (const float*)d_in[0];
    const float* vfirst = (const float*)d_in[1];
    const float* state  = (const float*)d_in[2];
    const int*   cpos   = (const int*)d_in[3];
    const float* w0 = (const float*)d_in[4];
    const float* w1 = (const float*)d_in[5];
    const float* w2 = (const float*)d_in[6];
    const float* a0 = (const float*)d_in[7];
    const float* a1 = (const float*)d_in[8];
    const float* a2 = (const float*)d_in[9];
    const float* v0 = (const float*)d_in[10];
    const float* v1 = (const float*)d_in[11];
    const float* v2 = (const float*)d_in[12];
    const float* g1 = (const float*)d_in[13];
    const float* g2 = (const float*)d_in[14];
    const float* r_k = (const float*)d_in[15];
    const float* R_ = (const float*)d_in[16];
    const float* K_ = (const float*)d_in[17];
    const float* V_ = (const float*)d_in[18];
    const float* O_ = (const float*)d_in[19];
    const float* Rb = (const float*)d_in[20];
    const float* Kb = (const float*)d_in[21];
    const float* Vb = (const float*)d_in[22];
    const float* ln_r = (const float*)d_in[23];
    const float* ln_k = (const float*)d_in[24];
    const float* ln1 = (const float*)d_in[25];
    const float* ln2 = (const float*)d_in[26];

    float* ws = (float*)d_ws;
    // ---- workspace map (units: f32 slots). TCB = 256*320 bf16 = 40960 f32 slots.
    // YB aliases XB: XB (read by gemm_rkvt) is dead before scan_k writes YB.
    constexpr size_t OFF_XB   = 0;          // bf16 [256][4096] = 524288 f32
    constexpr size_t OFF_COMB = 524288;     // f32 [256][6464]  = 1654784
    constexpr size_t OFF_WT   = 2179072;    // f32 [320][4096]  = 1310720
    constexpr size_t OFF_TCB  = 3489792;    // bf16 [256][320]  = 40960 f32
    constexpr size_t OFF_WPRE = 3530752;    // f32 [256][4096]
    constexpr size_t OFF_APRE = 4579328;
    constexpr size_t OFF_VGPRE= 5627904;
    constexpr size_t OFF_G    = 6676480;
    constexpr size_t OFF_COS  = 7725056;    // 16384
    constexpr size_t OFF_SIN  = 7741440;    // 16384
    constexpr size_t OFF_RF   = 7757824;    // 6 x 1048576
    constexpr size_t OFF_WF   = 8806400;
    constexpr size_t OFF_KF   = 9854976;
    constexpr size_t OFF_VF   = 10903552;
    constexpr size_t OFF_AF   = 11952128;
    constexpr size_t OFF_BF   = 13000704;
    constexpr size_t OFF_YB   = OFF_XB;     // alias (see above)

    ushort* XB  = (ushort*)(ws + OFF_XB);
    float* COMB = ws + OFF_COMB;
    float* WT   = ws + OFF_WT;
    ushort* TCB = (ushort*)(ws + OFF_TCB);
    float* WPRE = ws + OFF_WPRE;
    float* APRE = ws + OFF_APRE;
    float* VGPRE= ws + OFF_VGPRE;
    float* GARR = ws + OFF_G;
    float* COST = ws + OFF_COS;
    float* SINT = ws + OFF_SIN;
    float* RF = ws + OFF_RF;
    float* WF = ws + OFF_WF;
    float* KF = ws + OFF_KF;
    float* VF = ws + OFF_VF;
    float* AF = ws + OFF_AF;
    float* BF = ws + OFF_BF;
    ushort* YB = (ushort*)(ws + OFF_YB);

    float* out = (float*)d_out;
    float* out0  = out;                 // (1,256,4096)
    float* xlast = out + 1048576;       // (1,4096)
    float* Sfin  = out + 1052672;       // (1,32,128,128)
    float* vfout = out + 1576960;       // (1,256,4096)
    float* xres  = out + 2625536;       // (1,256,4096)

    hipMemcpyAsync(vfout, vfirst, (size_t)1048576 * 4, hipMemcpyDeviceToDevice, stream);
    hipMemcpyAsync(xres, x_in, (size_t)1048576 * 4, hipMemcpyDeviceToDevice, stream);

    rmsnorm_k<<<T_, 256, 0, stream>>>(x_in, ln1, nullptr, XB, xlast);

    wcat2_k<<<dim3(64, 5), 256, 0, stream>>>(w1, a1, v1, g1, WT);
    hipMemsetAsync(WT + (size_t)288 * 4096, 0, (size_t)32 * 4096 * 4, stream);
    init_comb_k<<<T_, 256, 0, stream>>>(Rb, Kb, Vb, COMB);

    gemm_rkvt<<<dim3(202, 4), 512, 0, stream>>>(XB, R_, K_, V_, WT, COMB, 1024);

    act_k<<<288, 256, 0, stream>>>(COMB, TCB);

    gemm_s2<<<dim3(128, 4), 512, 0, stream>>>(TCB, w2, a2, v2, g2, w0, a0, v0,
                                              WPRE, APRE, VGPRE, GARR);

    rope_k<<<64, 256, 0, stream>>>(cpos, COST, SINT);

    prep_k<<<T_, 256, 0, stream>>>(COMB, WPRE, APRE, VGPRE, vfirst,
                                   COST, SINT, ln_r, ln_k, RF, WF, KF, VF, AF, BF);

    scan_k<<<dim3(8, 32), 256, 0, stream>>>(state, RF, WF, KF, VF, AF, BF, r_k, GARR, YB, Sfin);

    gemm_o<<<dim3(128, 4), 512, 0, stream>>>(YB, O_, xres, 1024);

    rmsnorm_k<<<T_, 256, 0, stream>>>(xres, ln2, out0, nullptr, nullptr);
}

// Round 5
// 523.955 us; speedup vs baseline: 2.9409x; 1.0478x over previous
//
#include <hip/hip_runtime.h>
#include <cstdint>
#include <cstddef>

#define T_ 256
#define HN_ 4096
#define H_ 32
#define N_ 128
#define SR_ 6464   // COMB row stride (4096 R + 1024 K + 1024 V + 320 T)

typedef __attribute__((ext_vector_type(8))) short short8;
typedef __attribute__((ext_vector_type(4))) float f32x4;

__device__ __forceinline__ short f2bf(float f) {
    uint32_t u = __builtin_bit_cast(uint32_t, f);
    u = (u + 0x7fffu + ((u >> 16) & 1u)) >> 16;   // RNE f32->bf16
    return (short)u;
}
__device__ __forceinline__ short f2bfc(float f) {  // cheap round-half-up
    return (short)((__builtin_bit_cast(uint32_t, f) + 0x8000u) >> 16);
}
__device__ __forceinline__ short8 cvt8(const float* p) {
    float4 lo = *(const float4*)p, hi = *(const float4*)(p + 4);
    short8 v;
    v[0] = f2bfc(lo.x); v[1] = f2bfc(lo.y); v[2] = f2bfc(lo.z); v[3] = f2bfc(lo.w);
    v[4] = f2bfc(hi.x); v[5] = f2bfc(hi.y); v[6] = f2bfc(hi.z); v[7] = f2bfc(hi.w);
    return v;
}
__device__ __forceinline__ f32x4 mfma16(short8 a, short8 b, f32x4 c) {
    return __builtin_amdgcn_mfma_f32_16x16x32_bf16(a, b, c, 0, 0, 0);
}
__device__ __forceinline__ float sigm(float x) { return 1.f / (1.f + expf(-x)); }
__device__ __forceinline__ float splus(float x) { return (x > 20.f) ? x : log1pf(expf(x)); }

__device__ __forceinline__ float bf1(ushort u) {
    return __builtin_bit_cast(float, (uint32_t)u << 16);
}
__device__ __forceinline__ void bf4(float* d, const ushort* p) {
    uint2 u = *(const uint2*)p;
    d[0] = __builtin_bit_cast(float, u.x << 16);
    d[1] = __builtin_bit_cast(float, u.x & 0xffff0000u);
    d[2] = __builtin_bit_cast(float, u.y << 16);
    d[3] = __builtin_bit_cast(float, u.y & 0xffff0000u);
}
__device__ __forceinline__ void gload_lds16(const void* g, void* l) {
    __builtin_amdgcn_global_load_lds(
        (const __attribute__((address_space(1))) void*)g,
        (__attribute__((address_space(3))) void*)l, 16, 0, 0);
}

// ---------------- RMSNorm over 4096; optional f32 out, bf16 out, lastrow ----------
__global__ __launch_bounds__(256) void rmsnorm_k(const float* __restrict__ in,
                                                 const float* __restrict__ w,
                                                 float* __restrict__ outF,
                                                 ushort* __restrict__ outB,
                                                 float* __restrict__ lastrow) {
    int t = blockIdx.x, tid = threadIdx.x;
    const float4* in4 = (const float4*)(in + (size_t)t * HN_);
    const float4* w4 = (const float4*)w;
    float4 v[4]; float ss = 0.f;
#pragma unroll
    for (int q = 0; q < 4; q++) {
        v[q] = in4[q * 256 + tid];
        ss += v[q].x * v[q].x + v[q].y * v[q].y + v[q].z * v[q].z + v[q].w * v[q].w;
    }
#pragma unroll
    for (int o = 32; o; o >>= 1) ss += __shfl_down(ss, o);
    __shared__ float red[4];
    if ((tid & 63) == 0) red[tid >> 6] = ss;
    __syncthreads();
    float tot = red[0] + red[1] + red[2] + red[3];
    float sc = rsqrtf(tot * (1.f / HN_) + 1e-6f);
#pragma unroll
    for (int q = 0; q < 4; q++) {
        float4 wv = w4[q * 256 + tid];
        float4 r;
        r.x = wv.x * v[q].x * sc; r.y = wv.y * v[q].y * sc;
        r.z = wv.z * v[q].z * sc; r.w = wv.w * v[q].w * sc;
        int idx = q * 256 + tid;
        if (outF) ((float4*)(outF + (size_t)t * HN_))[idx] = r;
        if (outB) {
            ushort4 b;
            b.x = (ushort)f2bf(r.x); b.y = (ushort)f2bf(r.y);
            b.z = (ushort)f2bf(r.z); b.w = (ushort)f2bf(r.w);
            ((ushort4*)(outB + (size_t)t * HN_))[idx] = b;
        }
        if (lastrow && t == T_ - 1) ((float4*)lastrow)[idx] = r;
    }
}

// ---------------- fused R/K/V/LoRA1 split-K GEMM, atomic epilogue into COMB ------
__global__ __launch_bounds__(512) void gemm_rkvt(
    const ushort* __restrict__ A,          // XB [256][4096] bf16
    const float* __restrict__ Rw, const float* __restrict__ Kw,
    const float* __restrict__ Vw, const float* __restrict__ WT,
    float* __restrict__ COMB, int kchunk) {
    const int tid = threadIdx.x, wid = tid >> 6, l = tid & 63;
    const int ar = l & 15, ak = (l >> 4) * 8;
    const int mBase = wid * 32;
    const int nB = blockIdx.x * 32;
    const int kbeg = blockIdx.y * kchunk;

    const float* Bp; int brow;
    if (nB < 4096)      { Bp = Rw; brow = nB; }
    else if (nB < 5120) { Bp = Kw; brow = nB - 4096; }
    else if (nB < 6144) { Bp = Vw; brow = nB - 5120; }
    else                { Bp = WT; brow = nB - 6144; }

    f32x4 acc[2][2];
#pragma unroll
    for (int i = 0; i < 2; i++)
#pragma unroll
        for (int j = 0; j < 2; j++) acc[i][j] = f32x4{0.f, 0.f, 0.f, 0.f};

    const ushort* pA0 = A + (size_t)(mBase + ar) * 4096 + kbeg + ak;
    const ushort* pA1 = pA0 + (size_t)16 * 4096;
    const float* pB0 = Bp + (size_t)(brow + ar) * 4096 + kbeg + ak;
    const float* pB1 = pB0 + (size_t)16 * 4096;

    for (int ks = 0; ks < kchunk; ks += 32) {
        short8 a0 = *(const short8*)pA0; pA0 += 32;
        short8 a1 = *(const short8*)pA1; pA1 += 32;
        short8 b0 = cvt8(pB0); pB0 += 32;
        short8 b1 = cvt8(pB1); pB1 += 32;
        acc[0][0] = mfma16(a0, b0, acc[0][0]);
        acc[0][1] = mfma16(a0, b1, acc[0][1]);
        acc[1][0] = mfma16(a1, b0, acc[1][0]);
        acc[1][1] = mfma16(a1, b1, acc[1][1]);
    }
    const int rl = (l >> 4) * 4, cl = l & 15;
#pragma unroll
    for (int mf = 0; mf < 2; mf++)
#pragma unroll
        for (int nf = 0; nf < 2; nf++)
#pragma unroll
            for (int e = 0; e < 4; e++)
                unsafeAtomicAdd(&COMB[(size_t)(mBase + mf * 16 + rl + e) * SR_ + nB + nf * 16 + cl],
                                acc[mf][nf][e]);
}

// ---------------- O GEMM: xres += YB @ O^T (atomic, split-K) ---------------------
__global__ __launch_bounds__(512) void gemm_o(
    const ushort* __restrict__ A,          // YB [256][4096] bf16
    const float* __restrict__ B,           // O_ [4096][4096] TN
    float* __restrict__ C, int kchunk) {
    const int tid = threadIdx.x, wid = tid >> 6, l = tid & 63;
    const int ar = l & 15, ak = (l >> 4) * 8;
    const int mBase = wid * 32;
    const int nB = blockIdx.x * 32;
    const int kbeg = blockIdx.y * kchunk;

    f32x4 acc[2][2];
#pragma unroll
    for (int i = 0; i < 2; i++)
#pragma unroll
        for (int j = 0; j < 2; j++) acc[i][j] = f32x4{0.f, 0.f, 0.f, 0.f};

    const ushort* pA0 = A + (size_t)(mBase + ar) * 4096 + kbeg + ak;
    const ushort* pA1 = pA0 + (size_t)16 * 4096;
    const float* pB0 = B + (size_t)(nB + ar) * 4096 + kbeg + ak;
    const float* pB1 = pB0 + (size_t)16 * 4096;

    for (int ks = 0; ks < kchunk; ks += 32) {
        short8 a0 = *(const short8*)pA0; pA0 += 32;
        short8 a1 = *(const short8*)pA1; pA1 += 32;
        short8 b0 = cvt8(pB0); pB0 += 32;
        short8 b1 = cvt8(pB1); pB1 += 32;
        acc[0][0] = mfma16(a0, b0, acc[0][0]);
        acc[0][1] = mfma16(a0, b1, acc[0][1]);
        acc[1][0] = mfma16(a1, b0, acc[1][0]);
        acc[1][1] = mfma16(a1, b1, acc[1][1]);
    }
    const int rl = (l >> 4) * 4, cl = l & 15;
#pragma unroll
    for (int mf = 0; mf < 2; mf++)
#pragma unroll
        for (int nf = 0; nf < 2; nf++)
#pragma unroll
            for (int e = 0; e < 4; e++)
                unsafeAtomicAdd(&C[(size_t)(mBase + mf * 16 + rl + e) * 4096 + nB + nf * 16 + cl],
                                acc[mf][nf][e]);
}

// ---------------- fused stage-2 LoRA GEMMs (4 segments via blockIdx.y) -----------
__global__ __launch_bounds__(512) void gemm_s2(
    const ushort* __restrict__ TCB,        // [256][320] bf16
    const float* __restrict__ w2, const float* __restrict__ a2,
    const float* __restrict__ v2, const float* __restrict__ g2,
    const float* __restrict__ w0, const float* __restrict__ a0,
    const float* __restrict__ v0,
    float* __restrict__ WPRE, float* __restrict__ APRE,
    float* __restrict__ VGPRE, float* __restrict__ GARR) {
    const int z = blockIdx.y;
    int Aoff, K; const float* B; const float* bias; float* out;
    if (z == 0)      { Aoff = 0;   K = 64;  B = w2; bias = w0;      out = WPRE; }
    else if (z == 1) { Aoff = 64;  K = 64;  B = a2; bias = a0;      out = APRE; }
    else if (z == 2) { Aoff = 128; K = 32;  B = v2; bias = v0;      out = VGPRE; }
    else             { Aoff = 160; K = 128; B = g2; bias = nullptr; out = GARR; }

    const int tid = threadIdx.x, wid = tid >> 6, l = tid & 63;
    const int ar = l & 15, ak = (l >> 4) * 8;
    const int mBase = wid * 32;
    const int nB = blockIdx.x * 32;

    f32x4 acc[2][2];
#pragma unroll
    for (int i = 0; i < 2; i++)
#pragma unroll
        for (int j = 0; j < 2; j++) acc[i][j] = f32x4{0.f, 0.f, 0.f, 0.f};

    for (int k0 = 0; k0 < K; k0 += 32) {
        const ushort* pA = TCB + (size_t)(mBase + ar) * 320 + Aoff + k0 + ak;
        short8 av0 = *(const short8*)pA;
        short8 av1 = *(const short8*)(pA + (size_t)16 * 320);
        short8 bv0, bv1;
#pragma unroll
        for (int e = 0; e < 8; e++) {
            bv0[e] = f2bfc(B[(size_t)(k0 + ak + e) * 4096 + nB + ar]);
            bv1[e] = f2bfc(B[(size_t)(k0 + ak + e) * 4096 + nB + 16 + ar]);
        }
        acc[0][0] = mfma16(av0, bv0, acc[0][0]);
        acc[0][1] = mfma16(av0, bv1, acc[0][1]);
        acc[1][0] = mfma16(av1, bv0, acc[1][0]);
        acc[1][1] = mfma16(av1, bv1, acc[1][1]);
    }
    const int rl = (l >> 4) * 4, cl = l & 15;
#pragma unroll
    for (int mf = 0; mf < 2; mf++)
#pragma unroll
        for (int nf = 0; nf < 2; nf++) {
            int col = nB + nf * 16 + cl;
            float bv = bias ? bias[col] : 0.f;
#pragma unroll
            for (int e = 0; e < 4; e++)
                out[(size_t)(mBase + mf * 16 + rl + e) * 4096 + col] = acc[mf][nf][e] + bv;
        }
}

// ---------------- LoRA-A concat-transpose via LDS tiles -> WT[320][4096] ---------
__global__ __launch_bounds__(256) void wcat2_k(const float* __restrict__ w1p,
                                               const float* __restrict__ a1p,
                                               const float* __restrict__ v1p,
                                               const float* __restrict__ g1p,
                                               float* __restrict__ WT) {
    const int kb = blockIdx.x * 64, tile = blockIdx.y;
    const float* src; int ldw, jo, nb, W;
    if (tile == 0)      { src = w1p; ldw = 64;  jo = 0;  nb = 0;   W = 64; }
    else if (tile == 1) { src = a1p; ldw = 64;  jo = 0;  nb = 64;  W = 64; }
    else if (tile == 2) { src = v1p; ldw = 32;  jo = 0;  nb = 128; W = 32; }
    else if (tile == 3) { src = g1p; ldw = 128; jo = 0;  nb = 160; W = 64; }
    else                { src = g1p; ldw = 128; jo = 64; nb = 224; W = 64; }
    __shared__ float lds[64][65];
    const int ti = threadIdx.x & 63, wi = threadIdx.x >> 6;
    if (ti < W)
        for (int i = wi; i < 64; i += 4)
            lds[i][ti] = src[(size_t)(kb + i) * ldw + jo + ti];
    __syncthreads();
    for (int i2 = wi; i2 < W; i2 += 4)
        WT[(size_t)(nb + i2) * 4096 + kb + ti] = lds[ti][i2];
}

// ---------------- init COMB rows with biases (atomic GEMM accumulates on top) ----
__global__ __launch_bounds__(256) void init_comb_k(const float* __restrict__ Rb,
                                                   const float* __restrict__ Kb,
                                                   const float* __restrict__ Vb,
                                                   float* __restrict__ COMB) {
    int t = blockIdx.x;
    for (int c = threadIdx.x; c < SR_; c += 256) {
        float b = (c < 4096) ? Rb[c] : (c < 5120) ? Kb[c - 4096]
                : (c < 6144) ? Vb[c - 5120] : 0.f;
        COMB[(size_t)t * SR_ + c] = b;
    }
}

// ---------------- activations on TCAT cols of COMB -> TCB bf16 [256][320] --------
__global__ __launch_bounds__(256) void act_k(const float* __restrict__ COMB,
                                             ushort* __restrict__ TCB) {
    int idx = blockIdx.x * 256 + threadIdx.x;   // 256*288
    if (idx >= 256 * 288) return;
    int t = idx / 288, c = idx % 288;
    float v = COMB[(size_t)t * SR_ + 6144 + c];
    if (c < 64) v = tanhf(v);
    else if (c >= 160) v = sigm(v);
    TCB[t * 320 + c] = (ushort)f2bf(v);
}

// ---------------- RoPE cos/sin table [T][64] ----------------
__global__ void rope_k(const int* __restrict__ cpos, float* __restrict__ cosT,
                       float* __restrict__ sinT) {
    int idx = blockIdx.x * 256 + threadIdx.x;   // 16384 total
    int t = idx >> 6, f = idx & 63;
    float pos = (float)cpos[0] + (float)t;
    float mix = fminf(fmaxf(pos * (1.f / 4096.f), 0.f), 1.f);
    float e = (float)f * (1.f / 64.f);
    float inv_s = exp2f(-13.287712379549449f * e);
    float inv_l = exp2f(-13.287712379549449f - 3.321928094887362f * e);
    float fr = pos * ((1.f - mix) * inv_s + mix * inv_l);
    cosT[idx] = cosf(fr);
    sinT[idx] = sinf(fr);
}

// ---------------- elementwise prep -> packed scan stream SF ----------------------
// SF record per (h,t): 2048 B = bf16 r|k|v|a|b|g (6*128) + f32 decay (128)
__global__ __launch_bounds__(256) void prep_k(
    const float* __restrict__ COMB, const float* __restrict__ wpre,
    const float* __restrict__ apre, const float* __restrict__ vgpre,
    const float* __restrict__ vfirst, const float* __restrict__ garr,
    const float* __restrict__ cosT, const float* __restrict__ sinT,
    const float* __restrict__ lnr, const float* __restrict__ lnk,
    ushort* __restrict__ SFB) {
    int t = blockIdx.x, tid = threadIdx.x;
    int w = tid >> 6, lane = tid & 63;
    float c = cosT[t * 64 + lane], s = sinT[t * 64 + lane];
    float lr0 = lnr[lane], lr1 = lnr[lane + 64];
    float lk0 = lnk[lane], lk1 = lnk[lane + 64];
    const float* r_raw = COMB;
    const float* k_raw = COMB + 4096;
    const float* v_raw = COMB + 5120;
    for (int hb = 0; hb < 8; hb++) {
        int h = hb * 4 + w;
        int kv = h >> 2;
        float r0 = r_raw[(size_t)t * SR_ + h * 128 + lane];
        float r1 = r_raw[(size_t)t * SR_ + h * 128 + 64 + lane];
        float ssum = r0 * r0 + r1 * r1;
#pragma unroll
        for (int o = 32; o; o >>= 1) ssum += __shfl_xor(ssum, o);
        float sc = rsqrtf(ssum * (1.f / 128.f) + 1e-6f);
        float rn0 = lr0 * r0 * sc, rn1 = lr1 * r1 * sc;
        float rr0 = rn0 * c - rn1 * s;
        float rr1 = rn1 * c + rn0 * s;
        float k0 = k_raw[(size_t)t * SR_ + kv * 128 + lane];
        float k1 = k_raw[(size_t)t * SR_ + kv * 128 + 64 + lane];
        float ks = k0 * k0 + k1 * k1;
#pragma unroll
        for (int o = 32; o; o >>= 1) ks += __shfl_xor(ks, o);
        float ksc = rsqrtf(ks * (1.f / 128.f) + 1e-6f);
        float kn0 = lk0 * k0 * ksc, kn1 = lk1 * k1 * ksc;
        float kr0 = kn0 * c - kn1 * s;
        float kr1 = kn1 * c + kn0 * s;
        float nr = kr0 * kr0 + kr1 * kr1;
#pragma unroll
        for (int o = 32; o; o >>= 1) nr += __shfl_xor(nr, o);
        float inv = 1.f / fmaxf(sqrtf(nr), 1e-12f);
        float kk0 = kr0 * inv, kk1 = kr1 * inv;
        int c0 = h * 128 + lane, c1 = c0 + 64;
        size_t tb = (size_t)t * HN_;

        float wv0 = -splus(-wpre[tb + c0]) - 0.5f;
        float wv1 = -splus(-wpre[tb + c1]) - 0.5f;
        float dec0 = expf(-expf(wv0));
        float dec1 = expf(-expf(wv1));
        float av0 = sigm(apre[tb + c0]);
        float av1 = sigm(apre[tb + c1]);
        float vg0 = sigm(vgpre[tb + c0]);
        float vg1 = sigm(vgpre[tb + c1]);
        float vraw0 = v_raw[(size_t)t * SR_ + kv * 128 + lane];
        float vraw1 = v_raw[(size_t)t * SR_ + kv * 128 + 64 + lane];
        float vf0 = vraw0 + (vfirst[tb + c0] - vraw0) * vg0;
        float vf1 = vraw1 + (vfirst[tb + c1] - vraw1) * vg1;

        ushort* sb = SFB + ((size_t)h * T_ + t) * 1024;
        sb[lane]         = (ushort)f2bf(rr0);
        sb[64 + lane]    = (ushort)f2bf(rr1);
        sb[128 + lane]   = (ushort)f2bf(kr0 * (1.f - wv0 + av0));
        sb[192 + lane]   = (ushort)f2bf(kr1 * (1.f - wv1 + av1));
        sb[256 + lane]   = (ushort)f2bf(vf0);
        sb[320 + lane]   = (ushort)f2bf(vf1);
        sb[384 + lane]   = (ushort)f2bf(-kk0);
        sb[448 + lane]   = (ushort)f2bf(-kk1);
        sb[512 + lane]   = (ushort)f2bf(kk0 * av0);
        sb[576 + lane]   = (ushort)f2bf(kk1 * av1);
        sb[640 + lane]   = (ushort)f2bf(garr[tb + c0]);
        sb[704 + lane]   = (ushort)f2bf(garr[tb + c1]);
        float* sw = (float*)(sb + 768);
        sw[lane]      = dec0;
        sw[64 + lane] = dec1;
    }
}

// ---------------- sequential scan: 512 blocks = (16 row-splits x 32 heads) -------
// LDS double-buffered staging of the 2KB per-(h,t) record via global_load_lds.
__global__ __launch_bounds__(256) void scan_k(
    const float* __restrict__ state_in,
    const ushort* __restrict__ SFB,
    const float* __restrict__ rk,
    ushort* __restrict__ yb, float* __restrict__ Sout) {
    const int sp = blockIdx.x, h = blockIdx.y;
    const int tid = threadIdx.x;
    const int il = tid >> 5, jq = tid & 31;
    const int i = sp * 8 + il, j0 = jq * 4;
    const int wv = tid >> 6, ln = tid & 63;

    float S[4];
    {
        float4 s4 = *(const float4*)(state_in + ((size_t)h * 128 + i) * 128 + j0);
        S[0] = s4.x; S[1] = s4.y; S[2] = s4.z; S[3] = s4.w;
    }
    float4 rk4 = *(const float4*)(rk + h * 128 + j0);

    __shared__ __align__(16) ushort lds_s[2][1024];
    const ushort* hbase = SFB + (size_t)h * T_ * 1024;

    auto STAGE = [&](int buf, int t) {
        if (wv < 2) {
            const ushort* src = hbase + (size_t)t * 1024 + (wv * 64 + ln) * 8;
            gload_lds16(src, &lds_s[buf][wv * 512]);
        }
    };

    STAGE(0, 0);
    __syncthreads();

    int buf = 0;
    for (int t = 0; t < T_; t++) {
        if (t + 1 < T_) STAGE(buf ^ 1, t + 1);
        const ushort* L = &lds_s[buf][0];
        float r_[4], k_[4], a_[4], b_[4];
        bf4(r_, L + j0);
        bf4(k_, L + 128 + j0);
        bf4(a_, L + 384 + j0);
        bf4(b_, L + 512 + j0);
        float vi = bf1(L[256 + i]);
        const float* Ld = (const float*)(L + 768);
        float4 w4 = *(const float4*)&Ld[j0];

        float sa = fmaf(S[0], a_[0], fmaf(S[1], a_[1], fmaf(S[2], a_[2], S[3] * a_[3])));
        sa += __shfl_xor(sa, 1);  sa += __shfl_xor(sa, 2);
        sa += __shfl_xor(sa, 4);  sa += __shfl_xor(sa, 8);
        sa += __shfl_xor(sa, 16);

        S[0] = fmaf(vi, k_[0], fmaf(sa, b_[0], S[0] * w4.x));
        S[1] = fmaf(vi, k_[1], fmaf(sa, b_[1], S[1] * w4.y));
        S[2] = fmaf(vi, k_[2], fmaf(sa, b_[2], S[2] * w4.z));
        S[3] = fmaf(vi, k_[3], fmaf(sa, b_[3], S[3] * w4.w));

        float od = fmaf(S[0], r_[0], fmaf(S[1], r_[1], fmaf(S[2], r_[2], S[3] * r_[3])));
        float bd = fmaf(r_[0] * k_[0], rk4.x, fmaf(r_[1] * k_[1], rk4.y,
                   fmaf(r_[2] * k_[2], rk4.z, r_[3] * k_[3] * rk4.w)));
        float cp = fmaf(od, 0.08838834764831845f, bd * vi);
        cp += __shfl_xor(cp, 1);  cp += __shfl_xor(cp, 2);
        cp += __shfl_xor(cp, 4);  cp += __shfl_xor(cp, 8);
        cp += __shfl_xor(cp, 16);
        if (jq == 0) {
            float gv = bf1(L[640 + i]);
            yb[(size_t)t * HN_ + h * 128 + i] = (ushort)f2bf(cp * gv);
        }
        __syncthreads();
        buf ^= 1;
    }

    float* p = Sout + ((size_t)h * 128 + i) * 128 + j0;
    *(float4*)p = make_float4(S[0], S[1], S[2], S[3]);
}

// =====================================================================================
extern "C" void kernel_launch(void* const* d_in, const int* in_sizes, int n_in,
                              void* d_out, int out_size, void* d_ws, size_t ws_size,
                              hipStream_t stream) {
    const float* x_in   = (const float*)d_in[0];
    const float* vfirst = (const float*)d_in[1];
    const float* state  = (const float*)d_in[2];
    const int*   cpos   = (const int*)d_in[3];
    const float* w0 = (const float*)d_in[4];
    const float* w1 = (const float*)d_in[5];
    const float* w2 = (const float*)d_in[6];
    const float* a0 = (const float*)d_in[7];
    const float* a1 = (const float*)d_in[8];
    const float* a2 = (const float*)d_in[9];
    const float* v0 = (const float*)d_in[10];
    const float* v1 = (const float*)d_in[11];
    const float* v2 = (const float*)d_in[12];
    const float* g1 = (const float*)d_in[13];
    const float* g2 = (const float*)d_in[14];
    const float* r_k = (const float*)d_in[15];
    const float* R_ = (const float*)d_in[16];
    const float* K_ = (const float*)d_in[17];
    const float* V_ = (const float*)d_in[18];
    const float* O_ = (const float*)d_in[19];
    const float* Rb = (const float*)d_in[20];
    const float* Kb = (const float*)d_in[21];
    const float* Vb = (const float*)d_in[22];
    const float* ln_r = (const float*)d_in[23];
    const float* ln_k = (const float*)d_in[24];
    const float* ln1 = (const float*)d_in[25];
    const float* ln2 = (const float*)d_in[26];

    float* ws = (float*)d_ws;
    // ---- workspace map (units: f32 slots). YB aliases XB (XB dead before scan).
    constexpr size_t OFF_XB   = 0;          // bf16 [256][4096] = 524288 f32
    constexpr size_t OFF_COMB = 524288;     // f32 [256][6464]  = 1654784
    constexpr size_t OFF_WT   = 2179072;    // f32 [320][4096]  = 1310720
    constexpr size_t OFF_TCB  = 3489792;    // bf16 [256][320]  = 40960 f32
    constexpr size_t OFF_WPRE = 3530752;    // f32 [256][4096]
    constexpr size_t OFF_APRE = 4579328;
    constexpr size_t OFF_VGPRE= 5627904;
    constexpr size_t OFF_G    = 6676480;
    constexpr size_t OFF_COS  = 7725056;    // 16384
    constexpr size_t OFF_SIN  = 7741440;    // 16384
    constexpr size_t OFF_SF   = 7757824;    // packed scan stream: 32*256*2048B = 4194304 f32
    constexpr size_t OFF_YB   = OFF_XB;     // alias

    ushort* XB  = (ushort*)(ws + OFF_XB);
    float* COMB = ws + OFF_COMB;
    float* WT   = ws + OFF_WT;
    ushort* TCB = (ushort*)(ws + OFF_TCB);
    float* WPRE = ws + OFF_WPRE;
    float* APRE = ws + OFF_APRE;
    float* VGPRE= ws + OFF_VGPRE;
    float* GARR = ws + OFF_G;
    float* COST = ws + OFF_COS;
    float* SINT = ws + OFF_SIN;
    ushort* SFB = (ushort*)(ws + OFF_SF);
    ushort* YB  = (ushort*)(ws + OFF_YB);

    float* out = (float*)d_out;
    float* out0  = out;                 // (1,256,4096)
    float* xlast = out + 1048576;       // (1,4096)
    float* Sfin  = out + 1052672;       // (1,32,128,128)
    float* vfout = out + 1576960;       // (1,256,4096)
    float* xres  = out + 2625536;       // (1,256,4096)

    hipMemcpyAsync(vfout, vfirst, (size_t)1048576 * 4, hipMemcpyDeviceToDevice, stream);
    hipMemcpyAsync(xres, x_in, (size_t)1048576 * 4, hipMemcpyDeviceToDevice, stream);

    rmsnorm_k<<<T_, 256, 0, stream>>>(x_in, ln1, nullptr, XB, xlast);

    wcat2_k<<<dim3(64, 5), 256, 0, stream>>>(w1, a1, v1, g1, WT);
    hipMemsetAsync(WT + (size_t)288 * 4096, 0, (size_t)32 * 4096 * 4, stream);
    init_comb_k<<<T_, 256, 0, stream>>>(Rb, Kb, Vb, COMB);

    gemm_rkvt<<<dim3(202, 4), 512, 0, stream>>>(XB, R_, K_, V_, WT, COMB, 1024);

    act_k<<<288, 256, 0, stream>>>(COMB, TCB);

    gemm_s2<<<dim3(128, 4), 512, 0, stream>>>(TCB, w2, a2, v2, g2, w0, a0, v0,
                                              WPRE, APRE, VGPRE, GARR);

    rope_k<<<64, 256, 0, stream>>>(cpos, COST, SINT);

    prep_k<<<T_, 256, 0, stream>>>(COMB, WPRE, APRE, VGPRE, vfirst, GARR,
                                   COST, SINT, ln_r, ln_k, SFB);

    scan_k<<<dim3(16, 32), 256, 0, stream>>>(state, SFB, r_k, YB, Sfin);

    gemm_o<<<dim3(128, 4), 512, 0, stream>>>(YB, O_, xres, 1024);

    rmsnorm_k<<<T_, 256, 0, stream>>>(xres, ln2, out0, nullptr, nullptr);
}

// Round 6
// 493.196 us; speedup vs baseline: 3.1244x; 1.0624x over previous
//
#include <hip/hip_runtime.h>
#include <cstdint>
#include <cstddef>

#define T_ 256
#define HN_ 4096
#define H_ 32
#define N_ 128
#define SR_ 6464   // COMB row stride (4096 R + 1024 K + 1024 V + 320 T)

typedef __attribute__((ext_vector_type(8))) short short8;
typedef __attribute__((ext_vector_type(4))) float f32x4;

__device__ __forceinline__ short f2bf(float f) {
    uint32_t u = __builtin_bit_cast(uint32_t, f);
    u = (u + 0x7fffu + ((u >> 16) & 1u)) >> 16;   // RNE f32->bf16
    return (short)u;
}
__device__ __forceinline__ short f2bfc(float f) {  // cheap round-half-up
    return (short)((__builtin_bit_cast(uint32_t, f) + 0x8000u) >> 16);
}
__device__ __forceinline__ short8 cvt8(const float* p) {
    float4 lo = *(const float4*)p, hi = *(const float4*)(p + 4);
    short8 v;
    v[0] = f2bfc(lo.x); v[1] = f2bfc(lo.y); v[2] = f2bfc(lo.z); v[3] = f2bfc(lo.w);
    v[4] = f2bfc(hi.x); v[5] = f2bfc(hi.y); v[6] = f2bfc(hi.z); v[7] = f2bfc(hi.w);
    return v;
}
__device__ __forceinline__ f32x4 mfma16(short8 a, short8 b, f32x4 c) {
    return __builtin_amdgcn_mfma_f32_16x16x32_bf16(a, b, c, 0, 0, 0);
}
__device__ __forceinline__ float sigm(float x) { return 1.f / (1.f + expf(-x)); }
__device__ __forceinline__ float splus(float x) { return (x > 20.f) ? x : log1pf(expf(x)); }

__device__ __forceinline__ float bf1(ushort u) {
    return __builtin_bit_cast(float, (uint32_t)u << 16);
}
__device__ __forceinline__ void bf4(float* d, const ushort* p) {
    uint2 u = *(const uint2*)p;
    d[0] = __builtin_bit_cast(float, u.x << 16);
    d[1] = __builtin_bit_cast(float, u.x & 0xffff0000u);
    d[2] = __builtin_bit_cast(float, u.y << 16);
    d[3] = __builtin_bit_cast(float, u.y & 0xffff0000u);
}
__device__ __forceinline__ void gload_lds16(const void* g, void* l) {
    __builtin_amdgcn_global_load_lds(
        (const __attribute__((address_space(1))) void*)g,
        (__attribute__((address_space(3))) void*)l, 16, 0, 0);
}

// ---------------- RMSNorm over 4096; optional f32 out, bf16 out, lastrow ----------
__global__ __launch_bounds__(256) void rmsnorm_k(const float* __restrict__ in,
                                                 const float* __restrict__ w,
                                                 float* __restrict__ outF,
                                                 ushort* __restrict__ outB,
                                                 float* __restrict__ lastrow) {
    int t = blockIdx.x, tid = threadIdx.x;
    const float4* in4 = (const float4*)(in + (size_t)t * HN_);
    const float4* w4 = (const float4*)w;
    float4 v[4]; float ss = 0.f;
#pragma unroll
    for (int q = 0; q < 4; q++) {
        v[q] = in4[q * 256 + tid];
        ss += v[q].x * v[q].x + v[q].y * v[q].y + v[q].z * v[q].z + v[q].w * v[q].w;
    }
#pragma unroll
    for (int o = 32; o; o >>= 1) ss += __shfl_down(ss, o);
    __shared__ float red[4];
    if ((tid & 63) == 0) red[tid >> 6] = ss;
    __syncthreads();
    float tot = red[0] + red[1] + red[2] + red[3];
    float sc = rsqrtf(tot * (1.f / HN_) + 1e-6f);
#pragma unroll
    for (int q = 0; q < 4; q++) {
        float4 wv = w4[q * 256 + tid];
        float4 r;
        r.x = wv.x * v[q].x * sc; r.y = wv.y * v[q].y * sc;
        r.z = wv.z * v[q].z * sc; r.w = wv.w * v[q].w * sc;
        int idx = q * 256 + tid;
        if (outF) ((float4*)(outF + (size_t)t * HN_))[idx] = r;
        if (outB) {
            ushort4 b;
            b.x = (ushort)f2bf(r.x); b.y = (ushort)f2bf(r.y);
            b.z = (ushort)f2bf(r.z); b.w = (ushort)f2bf(r.w);
            ((ushort4*)(outB + (size_t)t * HN_))[idx] = b;
        }
        if (lastrow && t == T_ - 1) ((float4*)lastrow)[idx] = r;
    }
}

// ---------------- fused R/K/V/LoRA1 split-K GEMM, atomic epilogue into COMB ------
__global__ __launch_bounds__(512) void gemm_rkvt(
    const ushort* __restrict__ A,          // XB [256][4096] bf16
    const float* __restrict__ Rw, const float* __restrict__ Kw,
    const float* __restrict__ Vw, const float* __restrict__ WT,
    float* __restrict__ COMB, int kchunk) {
    const int tid = threadIdx.x, wid = tid >> 6, l = tid & 63;
    const int ar = l & 15, ak = (l >> 4) * 8;
    const int mBase = wid * 32;
    const int nB = blockIdx.x * 32;
    const int kbeg = blockIdx.y * kchunk;

    const float* Bp; int brow;
    if (nB < 4096)      { Bp = Rw; brow = nB; }
    else if (nB < 5120) { Bp = Kw; brow = nB - 4096; }
    else if (nB < 6144) { Bp = Vw; brow = nB - 5120; }
    else                { Bp = WT; brow = nB - 6144; }

    f32x4 acc[2][2];
#pragma unroll
    for (int i = 0; i < 2; i++)
#pragma unroll
        for (int j = 0; j < 2; j++) acc[i][j] = f32x4{0.f, 0.f, 0.f, 0.f};

    const ushort* pA0 = A + (size_t)(mBase + ar) * 4096 + kbeg + ak;
    const ushort* pA1 = pA0 + (size_t)16 * 4096;
    const float* pB0 = Bp + (size_t)(brow + ar) * 4096 + kbeg + ak;
    const float* pB1 = pB0 + (size_t)16 * 4096;

    for (int ks = 0; ks < kchunk; ks += 32) {
        short8 a0 = *(const short8*)pA0; pA0 += 32;
        short8 a1 = *(const short8*)pA1; pA1 += 32;
        short8 b0 = cvt8(pB0); pB0 += 32;
        short8 b1 = cvt8(pB1); pB1 += 32;
        acc[0][0] = mfma16(a0, b0, acc[0][0]);
        acc[0][1] = mfma16(a0, b1, acc[0][1]);
        acc[1][0] = mfma16(a1, b0, acc[1][0]);
        acc[1][1] = mfma16(a1, b1, acc[1][1]);
    }
    const int rl = (l >> 4) * 4, cl = l & 15;
#pragma unroll
    for (int mf = 0; mf < 2; mf++)
#pragma unroll
        for (int nf = 0; nf < 2; nf++)
#pragma unroll
            for (int e = 0; e < 4; e++)
                unsafeAtomicAdd(&COMB[(size_t)(mBase + mf * 16 + rl + e) * SR_ + nB + nf * 16 + cl],
                                acc[mf][nf][e]);
}

// ---------------- O GEMM: xres += YB @ O^T (atomic, split-K) ---------------------
__global__ __launch_bounds__(512) void gemm_o(
    const ushort* __restrict__ A,          // YB [256][4096] bf16
    const float* __restrict__ B,           // O_ [4096][4096] TN
    float* __restrict__ C, int kchunk) {
    const int tid = threadIdx.x, wid = tid >> 6, l = tid & 63;
    const int ar = l & 15, ak = (l >> 4) * 8;
    const int mBase = wid * 32;
    const int nB = blockIdx.x * 32;
    const int kbeg = blockIdx.y * kchunk;

    f32x4 acc[2][2];
#pragma unroll
    for (int i = 0; i < 2; i++)
#pragma unroll
        for (int j = 0; j < 2; j++) acc[i][j] = f32x4{0.f, 0.f, 0.f, 0.f};

    const ushort* pA0 = A + (size_t)(mBase + ar) * 4096 + kbeg + ak;
    const ushort* pA1 = pA0 + (size_t)16 * 4096;
    const float* pB0 = B + (size_t)(nB + ar) * 4096 + kbeg + ak;
    const float* pB1 = pB0 + (size_t)16 * 4096;

    for (int ks = 0; ks < kchunk; ks += 32) {
        short8 a0 = *(const short8*)pA0; pA0 += 32;
        short8 a1 = *(const short8*)pA1; pA1 += 32;
        short8 b0 = cvt8(pB0); pB0 += 32;
        short8 b1 = cvt8(pB1); pB1 += 32;
        acc[0][0] = mfma16(a0, b0, acc[0][0]);
        acc[0][1] = mfma16(a0, b1, acc[0][1]);
        acc[1][0] = mfma16(a1, b0, acc[1][0]);
        acc[1][1] = mfma16(a1, b1, acc[1][1]);
    }
    const int rl = (l >> 4) * 4, cl = l & 15;
#pragma unroll
    for (int mf = 0; mf < 2; mf++)
#pragma unroll
        for (int nf = 0; nf < 2; nf++)
#pragma unroll
            for (int e = 0; e < 4; e++)
                unsafeAtomicAdd(&C[(size_t)(mBase + mf * 16 + rl + e) * 4096 + nB + nf * 16 + cl],
                                acc[mf][nf][e]);
}

// ---------------- fused stage-2 LoRA GEMMs (4 segments via blockIdx.y) -----------
__global__ __launch_bounds__(512) void gemm_s2(
    const ushort* __restrict__ TCB,        // [256][320] bf16
    const float* __restrict__ w2, const float* __restrict__ a2,
    const float* __restrict__ v2, const float* __restrict__ g2,
    const float* __restrict__ w0, const float* __restrict__ a0,
    const float* __restrict__ v0,
    float* __restrict__ WPRE, float* __restrict__ APRE,
    float* __restrict__ VGPRE, float* __restrict__ GARR) {
    const int z = blockIdx.y;
    int Aoff, K; const float* B; const float* bias; float* out;
    if (z == 0)      { Aoff = 0;   K = 64;  B = w2; bias = w0;      out = WPRE; }
    else if (z == 1) { Aoff = 64;  K = 64;  B = a2; bias = a0;      out = APRE; }
    else if (z == 2) { Aoff = 128; K = 32;  B = v2; bias = v0;      out = VGPRE; }
    else             { Aoff = 160; K = 128; B = g2; bias = nullptr; out = GARR; }

    const int tid = threadIdx.x, wid = tid >> 6, l = tid & 63;
    const int ar = l & 15, ak = (l >> 4) * 8;
    const int mBase = wid * 32;
    const int nB = blockIdx.x * 32;

    f32x4 acc[2][2];
#pragma unroll
    for (int i = 0; i < 2; i++)
#pragma unroll
        for (int j = 0; j < 2; j++) acc[i][j] = f32x4{0.f, 0.f, 0.f, 0.f};

    for (int k0 = 0; k0 < K; k0 += 32) {
        const ushort* pA = TCB + (size_t)(mBase + ar) * 320 + Aoff + k0 + ak;
        short8 av0 = *(const short8*)pA;
        short8 av1 = *(const short8*)(pA + (size_t)16 * 320);
        short8 bv0, bv1;
#pragma unroll
        for (int e = 0; e < 8; e++) {
            bv0[e] = f2bfc(B[(size_t)(k0 + ak + e) * 4096 + nB + ar]);
            bv1[e] = f2bfc(B[(size_t)(k0 + ak + e) * 4096 + nB + 16 + ar]);
        }
        acc[0][0] = mfma16(av0, bv0, acc[0][0]);
        acc[0][1] = mfma16(av0, bv1, acc[0][1]);
        acc[1][0] = mfma16(av1, bv0, acc[1][0]);
        acc[1][1] = mfma16(av1, bv1, acc[1][1]);
    }
    const int rl = (l >> 4) * 4, cl = l & 15;
#pragma unroll
    for (int mf = 0; mf < 2; mf++)
#pragma unroll
        for (int nf = 0; nf < 2; nf++) {
            int col = nB + nf * 16 + cl;
            float bv = bias ? bias[col] : 0.f;
#pragma unroll
            for (int e = 0; e < 4; e++)
                out[(size_t)(mBase + mf * 16 + rl + e) * 4096 + col] = acc[mf][nf][e] + bv;
        }
}

// ---------------- LoRA-A concat-transpose via LDS tiles -> WT[320][4096] ---------
__global__ __launch_bounds__(256) void wcat2_k(const float* __restrict__ w1p,
                                               const float* __restrict__ a1p,
                                               const float* __restrict__ v1p,
                                               const float* __restrict__ g1p,
                                               float* __restrict__ WT) {
    const int kb = blockIdx.x * 64, tile = blockIdx.y;
    const float* src; int ldw, jo, nb, W;
    if (tile == 0)      { src = w1p; ldw = 64;  jo = 0;  nb = 0;   W = 64; }
    else if (tile == 1) { src = a1p; ldw = 64;  jo = 0;  nb = 64;  W = 64; }
    else if (tile == 2) { src = v1p; ldw = 32;  jo = 0;  nb = 128; W = 32; }
    else if (tile == 3) { src = g1p; ldw = 128; jo = 0;  nb = 160; W = 64; }
    else                { src = g1p; ldw = 128; jo = 64; nb = 224; W = 64; }
    __shared__ float lds[64][65];
    const int ti = threadIdx.x & 63, wi = threadIdx.x >> 6;
    if (ti < W)
        for (int i = wi; i < 64; i += 4)
            lds[i][ti] = src[(size_t)(kb + i) * ldw + jo + ti];
    __syncthreads();
    for (int i2 = wi; i2 < W; i2 += 4)
        WT[(size_t)(nb + i2) * 4096 + kb + ti] = lds[ti][i2];
}

// ---------------- init COMB rows with biases (atomic GEMM accumulates on top) ----
__global__ __launch_bounds__(256) void init_comb_k(const float* __restrict__ Rb,
                                                   const float* __restrict__ Kb,
                                                   const float* __restrict__ Vb,
                                                   float* __restrict__ COMB) {
    int t = blockIdx.x;
    for (int c = threadIdx.x; c < SR_; c += 256) {
        float b = (c < 4096) ? Rb[c] : (c < 5120) ? Kb[c - 4096]
                : (c < 6144) ? Vb[c - 5120] : 0.f;
        COMB[(size_t)t * SR_ + c] = b;
    }
}

// ---------------- activations on TCAT cols of COMB -> TCB bf16 [256][320] --------
__global__ __launch_bounds__(256) void act_k(const float* __restrict__ COMB,
                                             ushort* __restrict__ TCB) {
    int idx = blockIdx.x * 256 + threadIdx.x;   // 256*288
    if (idx >= 256 * 288) return;
    int t = idx / 288, c = idx % 288;
    float v = COMB[(size_t)t * SR_ + 6144 + c];
    if (c < 64) v = tanhf(v);
    else if (c >= 160) v = sigm(v);
    TCB[t * 320 + c] = (ushort)f2bf(v);
}

// ---------------- RoPE cos/sin table [T][64] ----------------
__global__ void rope_k(const int* __restrict__ cpos, float* __restrict__ cosT,
                       float* __restrict__ sinT) {
    int idx = blockIdx.x * 256 + threadIdx.x;   // 16384 total
    int t = idx >> 6, f = idx & 63;
    float pos = (float)cpos[0] + (float)t;
    float mix = fminf(fmaxf(pos * (1.f / 4096.f), 0.f), 1.f);
    float e = (float)f * (1.f / 64.f);
    float inv_s = exp2f(-13.287712379549449f * e);
    float inv_l = exp2f(-13.287712379549449f - 3.321928094887362f * e);
    float fr = pos * ((1.f - mix) * inv_s + mix * inv_l);
    cosT[idx] = cosf(fr);
    sinT[idx] = sinf(fr);
}

// ---------------- elementwise prep -> packed scan stream SF ----------------------
// SF record per (h,t): 2048 B = bf16 r|k|v|a|b|g (6*128) + f32 decay (128)
__global__ __launch_bounds__(256) void prep_k(
    const float* __restrict__ COMB, const float* __restrict__ wpre,
    const float* __restrict__ apre, const float* __restrict__ vgpre,
    const float* __restrict__ vfirst, const float* __restrict__ garr,
    const float* __restrict__ cosT, const float* __restrict__ sinT,
    const float* __restrict__ lnr, const float* __restrict__ lnk,
    ushort* __restrict__ SFB) {
    int t = blockIdx.x, tid = threadIdx.x;
    int w = tid >> 6, lane = tid & 63;
    float c = cosT[t * 64 + lane], s = sinT[t * 64 + lane];
    float lr0 = lnr[lane], lr1 = lnr[lane + 64];
    float lk0 = lnk[lane], lk1 = lnk[lane + 64];
    const float* r_raw = COMB;
    const float* k_raw = COMB + 4096;
    const float* v_raw = COMB + 5120;
    for (int hb = 0; hb < 8; hb++) {
        int h = hb * 4 + w;
        int kv = h >> 2;
        float r0 = r_raw[(size_t)t * SR_ + h * 128 + lane];
        float r1 = r_raw[(size_t)t * SR_ + h * 128 + 64 + lane];
        float ssum = r0 * r0 + r1 * r1;
#pragma unroll
        for (int o = 32; o; o >>= 1) ssum += __shfl_xor(ssum, o);
        float sc = rsqrtf(ssum * (1.f / 128.f) + 1e-6f);
        float rn0 = lr0 * r0 * sc, rn1 = lr1 * r1 * sc;
        float rr0 = rn0 * c - rn1 * s;
        float rr1 = rn1 * c + rn0 * s;
        float k0 = k_raw[(size_t)t * SR_ + kv * 128 + lane];
        float k1 = k_raw[(size_t)t * SR_ + kv * 128 + 64 + lane];
        float ks = k0 * k0 + k1 * k1;
#pragma unroll
        for (int o = 32; o; o >>= 1) ks += __shfl_xor(ks, o);
        float ksc = rsqrtf(ks * (1.f / 128.f) + 1e-6f);
        float kn0 = lk0 * k0 * ksc, kn1 = lk1 * k1 * ksc;
        float kr0 = kn0 * c - kn1 * s;
        float kr1 = kn1 * c + kn0 * s;
        float nr = kr0 * kr0 + kr1 * kr1;
#pragma unroll
        for (int o = 32; o; o >>= 1) nr += __shfl_xor(nr, o);
        float inv = 1.f / fmaxf(sqrtf(nr), 1e-12f);
        float kk0 = kr0 * inv, kk1 = kr1 * inv;
        int c0 = h * 128 + lane, c1 = c0 + 64;
        size_t tb = (size_t)t * HN_;

        float wv0 = -splus(-wpre[tb + c0]) - 0.5f;
        float wv1 = -splus(-wpre[tb + c1]) - 0.5f;
        float dec0 = expf(-expf(wv0));
        float dec1 = expf(-expf(wv1));
        float av0 = sigm(apre[tb + c0]);
        float av1 = sigm(apre[tb + c1]);
        float vg0 = sigm(vgpre[tb + c0]);
        float vg1 = sigm(vgpre[tb + c1]);
        float vraw0 = v_raw[(size_t)t * SR_ + kv * 128 + lane];
        float vraw1 = v_raw[(size_t)t * SR_ + kv * 128 + 64 + lane];
        float vf0 = vraw0 + (vfirst[tb + c0] - vraw0) * vg0;
        float vf1 = vraw1 + (vfirst[tb + c1] - vraw1) * vg1;

        ushort* sb = SFB + ((size_t)h * T_ + t) * 1024;
        sb[lane]         = (ushort)f2bf(rr0);
        sb[64 + lane]    = (ushort)f2bf(rr1);
        sb[128 + lane]   = (ushort)f2bf(kr0 * (1.f - wv0 + av0));
        sb[192 + lane]   = (ushort)f2bf(kr1 * (1.f - wv1 + av1));
        sb[256 + lane]   = (ushort)f2bf(vf0);
        sb[320 + lane]   = (ushort)f2bf(vf1);
        sb[384 + lane]   = (ushort)f2bf(-kk0);
        sb[448 + lane]   = (ushort)f2bf(-kk1);
        sb[512 + lane]   = (ushort)f2bf(kk0 * av0);
        sb[576 + lane]   = (ushort)f2bf(kk1 * av1);
        sb[640 + lane]   = (ushort)f2bf(garr[tb + c0]);
        sb[704 + lane]   = (ushort)f2bf(garr[tb + c1]);
        float* sw = (float*)(sb + 768);
        sw[lane]      = dec0;
        sw[64 + lane] = dec1;
    }
}

// ---------------- sequential scan, D=8 pipelined (counted vmcnt, raw barrier) ----
// grid (32 heads, 16 splits): linear block id % 8 == head % 8 -> per-head stream
// stays in one XCD's L2. Waves 0,1: stage loads only (exact vmcnt count).
// Wave 3: y-store for step t-1. ybuf double-buffered in LDS.
#define SD_ 8     // pipeline depth
#define SNB_ 9    // ring buffers = SD_+1
__global__ __launch_bounds__(256) void scan_k(
    const float* __restrict__ state_in,
    const ushort* __restrict__ SFB,
    const float* __restrict__ rk,
    ushort* __restrict__ yb, float* __restrict__ Sout) {
    const int h = blockIdx.x, sp = blockIdx.y;
    const int tid = threadIdx.x;
    const int il = tid >> 5, jq = tid & 31;
    const int i = sp * 8 + il, j0 = jq * 4;
    const int wv = tid >> 6, ln = tid & 63;

    float S[4];
    {
        float4 s4 = *(const float4*)(state_in + ((size_t)h * 128 + i) * 128 + j0);
        S[0] = s4.x; S[1] = s4.y; S[2] = s4.z; S[3] = s4.w;
    }
    float4 rk4 = *(const float4*)(rk + h * 128 + j0);

    __shared__ __align__(16) ushort lds_s[SNB_][1024];
    __shared__ float ybuf[2][8];
    const ushort* hbase = SFB + (size_t)h * T_ * 1024;

    auto STAGE = [&](int buf, int t) {
        if (wv < 2) {
            const ushort* src = hbase + (size_t)(t & (T_ - 1)) * 1024 + (wv * 64 + ln) * 8;
            gload_lds16(src, &lds_s[buf][wv * 512]);
        }
    };

#pragma unroll
    for (int d = 0; d < SD_; d++) STAGE(d, d);

    int bc = 0, bs = SD_;
    for (int t = 0; t < T_; t++) {
        if (wv < 2) asm volatile("s_waitcnt vmcnt(7)" ::: "memory");
        __builtin_amdgcn_s_barrier();
        __builtin_amdgcn_sched_barrier(0);
        asm volatile("" ::: "memory");

        STAGE(bs, t + SD_);                 // overwrites buffer consumed at t-1

        if (wv == 3 && ln < 8 && t > 0) {   // flush y for step t-1
            yb[(size_t)(t - 1) * HN_ + h * 128 + sp * 8 + ln] =
                (ushort)f2bf(ybuf[(t - 1) & 1][ln]);
        }

        const ushort* L = lds_s[bc];
        float r_[4], k_[4], a_[4], b_[4];
        bf4(r_, L + j0);
        bf4(k_, L + 128 + j0);
        bf4(a_, L + 384 + j0);
        bf4(b_, L + 512 + j0);
        float vi = bf1(L[256 + i]);
        const float* Ld = (const float*)(L + 768);
        float4 w4 = *(const float4*)&Ld[j0];

        float sa = fmaf(S[0], a_[0], fmaf(S[1], a_[1], fmaf(S[2], a_[2], S[3] * a_[3])));
        sa += __shfl_xor(sa, 1);  sa += __shfl_xor(sa, 2);
        sa += __shfl_xor(sa, 4);  sa += __shfl_xor(sa, 8);
        sa += __shfl_xor(sa, 16);

        S[0] = fmaf(vi, k_[0], fmaf(sa, b_[0], S[0] * w4.x));
        S[1] = fmaf(vi, k_[1], fmaf(sa, b_[1], S[1] * w4.y));
        S[2] = fmaf(vi, k_[2], fmaf(sa, b_[2], S[2] * w4.z));
        S[3] = fmaf(vi, k_[3], fmaf(sa, b_[3], S[3] * w4.w));

        float od = fmaf(S[0], r_[0], fmaf(S[1], r_[1], fmaf(S[2], r_[2], S[3] * r_[3])));
        float bd = fmaf(r_[0] * k_[0], rk4.x, fmaf(r_[1] * k_[1], rk4.y,
                   fmaf(r_[2] * k_[2], rk4.z, r_[3] * k_[3] * rk4.w)));
        float cp = fmaf(od, 0.08838834764831845f, bd * vi);
        cp += __shfl_xor(cp, 1);  cp += __shfl_xor(cp, 2);
        cp += __shfl_xor(cp, 4);  cp += __shfl_xor(cp, 8);
        cp += __shfl_xor(cp, 16);
        if (jq == 0) {
            float gv = bf1(L[640 + i]);
            ybuf[t & 1][il] = cp * gv;
        }

        bc = (bc + 1 == SNB_) ? 0 : bc + 1;
        bs = (bs + 1 == SNB_) ? 0 : bs + 1;
    }

    __builtin_amdgcn_s_barrier();
    asm volatile("" ::: "memory");
    if (wv == 3 && ln < 8) {
        yb[(size_t)(T_ - 1) * HN_ + h * 128 + sp * 8 + ln] =
            (ushort)f2bf(ybuf[(T_ - 1) & 1][ln]);
    }

    float* p = Sout + ((size_t)h * 128 + i) * 128 + j0;
    *(float4*)p = make_float4(S[0], S[1], S[2], S[3]);
}

// =====================================================================================
extern "C" void kernel_launch(void* const* d_in, const int* in_sizes, int n_in,
                              void* d_out, int out_size, void* d_ws, size_t ws_size,
                              hipStream_t stream) {
    const float* x_in   = (const float*)d_in[0];
    const float* vfirst = (const float*)d_in[1];
    const float* state  = (const float*)d_in[2];
    const int*   cpos   = (const int*)d_in[3];
    const float* w0 = (const float*)d_in[4];
    const float* w1 = (const float*)d_in[5];
    const float* w2 = (const float*)d_in[6];
    const float* a0 = (const float*)d_in[7];
    const float* a1 = (const float*)d_in[8];
    const float* a2 = (const float*)d_in[9];
    const float* v0 = (const float*)d_in[10];
    const float* v1 = (const float*)d_in[11];
    const float* v2 = (const float*)d_in[12];
    const float* g1 = (const float*)d_in[13];
    const float* g2 = (const float*)d_in[14];
    const float* r_k = (const float*)d_in[15];
    const float* R_ = (const float*)d_in[16];
    const float* K_ = (const float*)d_in[17];
    const float* V_ = (const float*)d_in[18];
    const float* O_ = (const float*)d_in[19];
    const float* Rb = (const float*)d_in[20];
    const float* Kb = (const float*)d_in[21];
    const float* Vb = (const float*)d_in[22];
    const float* ln_r = (const float*)d_in[23];
    const float* ln_k = (const float*)d_in[24];
    const float* ln1 = (const float*)d_in[25];
    const float* ln2 = (const float*)d_in[26];

    float* ws = (float*)d_ws;
    constexpr size_t OFF_XB   = 0;          // bf16 [256][4096] = 524288 f32
    constexpr size_t OFF_COMB = 524288;     // f32 [256][6464]  = 1654784
    constexpr size_t OFF_WT   = 2179072;    // f32 [320][4096]  = 1310720
    constexpr size_t OFF_TCB  = 3489792;    // bf16 [256][320]  = 40960 f32
    constexpr size_t OFF_WPRE = 3530752;    // f32 [256][4096]
    constexpr size_t OFF_APRE = 4579328;
    constexpr size_t OFF_VGPRE= 5627904;
    constexpr size_t OFF_G    = 6676480;
    constexpr size_t OFF_COS  = 7725056;    // 16384
    constexpr size_t OFF_SIN  = 7741440;    // 16384
    constexpr size_t OFF_SF   = 7757824;    // packed scan stream: 32*256*2048B
    constexpr size_t OFF_YB   = OFF_XB;     // alias (XB dead before scan)

    ushort* XB  = (ushort*)(ws + OFF_XB);
    float* COMB = ws + OFF_COMB;
    float* WT   = ws + OFF_WT;
    ushort* TCB = (ushort*)(ws + OFF_TCB);
    float* WPRE = ws + OFF_WPRE;
    float* APRE = ws + OFF_APRE;
    float* VGPRE= ws + OFF_VGPRE;
    float* GARR = ws + OFF_G;
    float* COST = ws + OFF_COS;
    float* SINT = ws + OFF_SIN;
    ushort* SFB = (ushort*)(ws + OFF_SF);
    ushort* YB  = (ushort*)(ws + OFF_YB);

    float* out = (float*)d_out;
    float* out0  = out;                 // (1,256,4096)
    float* xlast = out + 1048576;       // (1,4096)
    float* Sfin  = out + 1052672;       // (1,32,128,128)
    float* vfout = out + 1576960;       // (1,256,4096)
    float* xres  = out + 2625536;       // (1,256,4096)

    hipMemcpyAsync(vfout, vfirst, (size_t)1048576 * 4, hipMemcpyDeviceToDevice, stream);
    hipMemcpyAsync(xres, x_in, (size_t)1048576 * 4, hipMemcpyDeviceToDevice, stream);

    rmsnorm_k<<<T_, 256, 0, stream>>>(x_in, ln1, nullptr, XB, xlast);

    wcat2_k<<<dim3(64, 5), 256, 0, stream>>>(w1, a1, v1, g1, WT);
    hipMemsetAsync(WT + (size_t)288 * 4096, 0, (size_t)32 * 4096 * 4, stream);
    init_comb_k<<<T_, 256, 0, stream>>>(Rb, Kb, Vb, COMB);

    gemm_rkvt<<<dim3(202, 4), 512, 0, stream>>>(XB, R_, K_, V_, WT, COMB, 1024);

    act_k<<<288, 256, 0, stream>>>(COMB, TCB);

    gemm_s2<<<dim3(128, 4), 512, 0, stream>>>(TCB, w2, a2, v2, g2, w0, a0, v0,
                                              WPRE, APRE, VGPRE, GARR);

    rope_k<<<64, 256, 0, stream>>>(cpos, COST, SINT);

    prep_k<<<T_, 256, 0, stream>>>(COMB, WPRE, APRE, VGPRE, vfirst, GARR,
                                   COST, SINT, ln_r, ln_k, SFB);

    scan_k<<<dim3(32, 16), 256, 0, stream>>>(state, SFB, r_k, YB, Sfin);

    gemm_o<<<dim3(128, 4), 512, 0, stream>>>(YB, O_, xres, 1024);

    rmsnorm_k<<<T_, 256, 0, stream>>>(xres, ln2, out0, nullptr, nullptr);
}